// Round 1
// baseline (1500.665 us; speedup 1.0000x reference)
//
#include <hip/hip_runtime.h>

#define NN 100000
#define EE 1600000
#define FF 128
#define LL 4
#define GG 512
#define OUTC 10
#define EPSF 1e-5f

// ---------- graph setup ----------

__global__ __launch_bounds__(256) void k_deg(const int* __restrict__ col, int* __restrict__ deg) {
  int e = blockIdx.x * 256 + threadIdx.x;
  if (e < EE) atomicAdd(&deg[col[e]], 1);
}

__global__ __launch_bounds__(256) void k_dinv(const int* __restrict__ deg, float* __restrict__ dinv) {
  int n = blockIdx.x * 256 + threadIdx.x;
  if (n < NN) {
    int d = deg[n];
    dinv[n] = d > 0 ? rsqrtf((float)d) : 0.0f;
  }
}

// single-block exclusive scan of deg -> rowptr[0..NN]
__global__ __launch_bounds__(1024) void k_scan(const int* __restrict__ deg, int* __restrict__ rowptr) {
  __shared__ int ssum[1024];
  const int t = threadIdx.x;
  const int CH = (NN + 1023) / 1024;  // 98
  const int s = t * CH;
  const int e = min(s + CH, NN);
  int local = 0;
  for (int i = s; i < e; ++i) local += deg[i];
  ssum[t] = local;
  __syncthreads();
  for (int off = 1; off < 1024; off <<= 1) {
    int v = (t >= off) ? ssum[t - off] : 0;
    __syncthreads();
    ssum[t] += v;
    __syncthreads();
  }
  int base = (t == 0) ? 0 : ssum[t - 1];
  for (int i = s; i < e; ++i) {
    rowptr[i] = base;
    base += deg[i];
  }
  if (t == 1023) rowptr[NN] = ssum[1023];
}

__global__ __launch_bounds__(256) void k_fill(const int* __restrict__ ei,
                                              const int* __restrict__ rowptr,
                                              int* __restrict__ cnt,
                                              const float* __restrict__ dinv,
                                              int* __restrict__ csrc,
                                              float* __restrict__ cw) {
  int e = blockIdx.x * 256 + threadIdx.x;
  if (e >= EE) return;
  int r = ei[e];
  int cl = ei[EE + e];
  int slot = rowptr[cl] + atomicAdd(&cnt[cl], 1);
  csrc[slot] = r;
  cw[slot] = dinv[r] * dinv[cl];
}

// batch is sorted: gstart[g] = first node of graph g; gstart[GG] = NN
__global__ __launch_bounds__(256) void k_bounds(const int* __restrict__ batch, int* __restrict__ gstart) {
  int n = blockIdx.x * 256 + threadIdx.x;
  if (n >= NN) return;
  int b = batch[n];
  if (n == 0) {
    for (int g = 0; g <= b; ++g) gstart[g] = 0;
  } else {
    int bp = batch[n - 1];
    for (int g = bp + 1; g <= b; ++g) gstart[g] = n;
  }
  if (n == NN - 1) {
    for (int g = b + 1; g <= GG; ++g) gstart[g] = NN;
  }
}

// ---------- per-layer GEMM: C[N,128] = A[N,128] @ W[128,128] ----------
// block = 256 threads, tile = 64 rows x 128 cols, thread computes 4x8.
__global__ __launch_bounds__(256) void k_gemm(const float* __restrict__ A,
                                              const float* __restrict__ W,
                                              float* __restrict__ C) {
  __shared__ float sA[64 * 65];   // padded leading dim
  __shared__ float sW[64 * 128];
  const int tid = threadIdx.x;
  const int tx = tid & 15;
  const int ty = tid >> 4;
  const int tx8 = tx * 8;
  const int ty4 = ty * 4;
  const int rowbase = blockIdx.x * 64;

  float acc[4][8];
#pragma unroll
  for (int i = 0; i < 4; ++i)
#pragma unroll
    for (int j = 0; j < 8; ++j) acc[i][j] = 0.0f;

  for (int kc = 0; kc < 128; kc += 64) {
    // stage A tile: 64 rows x 64 k
#pragma unroll
    for (int i = 0; i < 4; ++i) {
      int li = tid + i * 256;       // 0..1023
      int r = li >> 4;              // 16 float4 per row
      int k4 = (li & 15) << 2;
      float4 v = make_float4(0.f, 0.f, 0.f, 0.f);
      int gr = rowbase + r;
      if (gr < NN) v = *(const float4*)(A + (size_t)gr * FF + kc + k4);
      sA[r * 65 + k4 + 0] = v.x;
      sA[r * 65 + k4 + 1] = v.y;
      sA[r * 65 + k4 + 2] = v.z;
      sA[r * 65 + k4 + 3] = v.w;
    }
    // stage W tile: 64 k x 128 cols
#pragma unroll
    for (int i = 0; i < 8; ++i) {
      int li = tid + i * 256;       // 0..2047
      int kk = li >> 5;             // 32 float4 per row
      int c4 = (li & 31) << 2;
      *(float4*)(sW + kk * 128 + c4) = *(const float4*)(W + (size_t)(kc + kk) * 128 + c4);
    }
    __syncthreads();
#pragma unroll 8
    for (int kk = 0; kk < 64; ++kk) {
      float av[4];
      av[0] = sA[(ty4 + 0) * 65 + kk];
      av[1] = sA[(ty4 + 1) * 65 + kk];
      av[2] = sA[(ty4 + 2) * 65 + kk];
      av[3] = sA[(ty4 + 3) * 65 + kk];
      float4 w0 = *(const float4*)(sW + kk * 128 + tx8);
      float4 w1 = *(const float4*)(sW + kk * 128 + tx8 + 4);
      float wv[8] = {w0.x, w0.y, w0.z, w0.w, w1.x, w1.y, w1.z, w1.w};
#pragma unroll
      for (int i = 0; i < 4; ++i)
#pragma unroll
        for (int j = 0; j < 8; ++j) acc[i][j] = fmaf(av[i], wv[j], acc[i][j]);
    }
    __syncthreads();
  }
#pragma unroll
  for (int i = 0; i < 4; ++i) {
    int gr = rowbase + ty4 + i;
    if (gr < NN) {
      float4 o0 = make_float4(acc[i][0], acc[i][1], acc[i][2], acc[i][3]);
      float4 o1 = make_float4(acc[i][4], acc[i][5], acc[i][6], acc[i][7]);
      *(float4*)(C + (size_t)gr * FF + tx8) = o0;
      *(float4*)(C + (size_t)gr * FF + tx8 + 4) = o1;
    }
  }
}

// ---------- aggregation: A[n] = relu(sum_e w*B[src] + bias), BN partials ----------
// one wave per node (grid-stride); lane handles channels 2*lane, 2*lane+1
__global__ __launch_bounds__(256) void k_agg(const float* __restrict__ B,
                                             const int* __restrict__ rowptr,
                                             const int* __restrict__ csrc,
                                             const float* __restrict__ cw,
                                             const float* __restrict__ bias,
                                             float* __restrict__ Aout,
                                             float* __restrict__ bnbuf) {
  const int lane = threadIdx.x & 63;
  const int wave = threadIdx.x >> 6;
  const int c = lane * 2;
  const int gwave = blockIdx.x * 4 + wave;
  const int nwaves = gridDim.x * 4;
  const float2 bv = *(const float2*)(bias + c);
  float s0 = 0.f, s1 = 0.f, q0 = 0.f, q1 = 0.f;
  for (int n = gwave; n < NN; n += nwaves) {
    const int beg = rowptr[n];
    const int end = rowptr[n + 1];
    float ax = 0.f, ay = 0.f;
    for (int j = beg; j < end; ++j) {
      const int src = csrc[j];
      const float w = cw[j];
      const float2 v = *(const float2*)(B + (size_t)src * FF + c);
      ax = fmaf(w, v.x, ax);
      ay = fmaf(w, v.y, ay);
    }
    ax = fmaxf(ax + bv.x, 0.f);
    ay = fmaxf(ay + bv.y, 0.f);
    *(float2*)(Aout + (size_t)n * FF + c) = make_float2(ax, ay);
    s0 += ax; s1 += ay;
    q0 = fmaf(ax, ax, q0); q1 = fmaf(ay, ay, q1);
  }
  __shared__ float sred[4][256];
  sred[wave][c] = s0;
  sred[wave][c + 1] = s1;
  sred[wave][128 + c] = q0;
  sred[wave][128 + c + 1] = q1;
  __syncthreads();
  const int t = threadIdx.x;
  float tot = sred[0][t] + sred[1][t] + sred[2][t] + sred[3][t];
  atomicAdd(&bnbuf[t], tot);
}

__global__ __launch_bounds__(128) void k_bnfin(const float* __restrict__ bnbuf,
                                               const float* __restrict__ gamma,
                                               const float* __restrict__ beta,
                                               float* __restrict__ bnsc) {
  const int c = threadIdx.x;
  float mu = bnbuf[c] * (1.0f / NN);
  float var = bnbuf[128 + c] * (1.0f / NN) - mu * mu;
  float inv = rsqrtf(var + EPSF);
  float sc = gamma[c] * inv;
  bnsc[c] = sc;
  bnsc[128 + c] = beta[c] - mu * sc;
}

// BN apply in-place + pooled (graph-sorted, 8 blocks per graph, 1 atomic/channel/block)
__global__ __launch_bounds__(128) void k_bnapply(float* __restrict__ A,
                                                 const float* __restrict__ bnsc,
                                                 const int* __restrict__ gstart,
                                                 float* __restrict__ pooledt) {
  const int g = blockIdx.x >> 3;
  const int sub = blockIdx.x & 7;
  const int s = gstart[g];
  const int e = gstart[g + 1];
  const int cnt = e - s;
  if (cnt <= 0) return;
  const int per = (cnt + 7) >> 3;
  const int ns = s + sub * per;
  const int ne = min(ns + per, e);
  if (ns >= ne) return;
  const int c = threadIdx.x;
  const float sc = bnsc[c];
  const float sh = bnsc[128 + c];
  float acc = 0.f;
  for (int n = ns; n < ne; ++n) {
    float v = fmaf(A[(size_t)n * FF + c], sc, sh);
    A[(size_t)n * FF + c] = v;
    acc += v;
  }
  atomicAdd(&pooledt[(size_t)g * 512 + c], acc);
}

// ---------- head ----------

__global__ __launch_bounds__(128) void k_z1(const float* __restrict__ pooled,
                                            const float* __restrict__ W1,
                                            const float* __restrict__ b1,
                                            float* __restrict__ z1) {
  __shared__ float sp[512];
  const int g = blockIdx.x;
  for (int i = threadIdx.x; i < 512; i += 128) sp[i] = pooled[(size_t)g * 512 + i];
  __syncthreads();
  const int c = threadIdx.x;
  float acc = b1[c];
  for (int j = 0; j < 512; ++j) acc = fmaf(sp[j], W1[j * 128 + c], acc);
  z1[(size_t)g * 128 + c] = acc;
}

__global__ __launch_bounds__(128) void k_zstat(const float* __restrict__ z1,
                                               const float* __restrict__ g1,
                                               const float* __restrict__ bt1,
                                               float* __restrict__ zsc) {
  const int c = threadIdx.x;
  float s = 0.f, q = 0.f;
  for (int g = 0; g < GG; ++g) {
    float v = z1[g * 128 + c];
    s += v;
    q = fmaf(v, v, q);
  }
  float mu = s * (1.0f / GG);
  float var = q * (1.0f / GG) - mu * mu;
  float inv = rsqrtf(var + EPSF);
  float sc = g1[c] * inv;
  zsc[c] = sc;
  zsc[128 + c] = bt1[c] - mu * sc;
}

__global__ __launch_bounds__(128) void k_out(const float* __restrict__ z1,
                                             const float* __restrict__ zsc,
                                             const float* __restrict__ W2,
                                             const float* __restrict__ b2,
                                             float* __restrict__ out) {
  __shared__ float zr[128];
  const int g = blockIdx.x;
  const int c = threadIdx.x;
  zr[c] = fmaxf(fmaf(z1[(size_t)g * 128 + c], zsc[c], zsc[128 + c]), 0.f);
  __syncthreads();
  if (c < OUTC) {
    float acc = b2[c];
    for (int k = 0; k < 128; ++k) acc = fmaf(zr[k], W2[k * OUTC + c], acc);
    out[(size_t)g * OUTC + c] = acc;
  }
}

// ---------- launch ----------

extern "C" void kernel_launch(void* const* d_in, const int* in_sizes, int n_in,
                              void* d_out, int out_size, void* d_ws, size_t ws_size,
                              hipStream_t stream) {
  const float* x      = (const float*)d_in[0];
  const int*   ei     = (const int*)d_in[1];
  const int*   batch  = (const int*)d_in[2];
  const float* Ws     = (const float*)d_in[3];
  const float* bs     = (const float*)d_in[4];
  const float* gammas = (const float*)d_in[5];
  const float* betas  = (const float*)d_in[6];
  const float* W1     = (const float*)d_in[7];
  const float* b1     = (const float*)d_in[8];
  const float* g1     = (const float*)d_in[9];
  const float* bt1    = (const float*)d_in[10];
  const float* W2     = (const float*)d_in[11];
  const float* b2     = (const float*)d_in[12];
  float* out = (float*)d_out;

  char* ws = (char*)d_ws;
  size_t off = 0;
  auto alloc = [&](size_t bytes) -> void* {
    void* p = ws + off;
    off = (off + bytes + 255) & ~(size_t)255;
    return p;
  };
  // zero-initialized region (single memset)
  int*   deg    = (int*)alloc((size_t)NN * 4);
  int*   cnt    = (int*)alloc((size_t)NN * 4);
  float* bnbuf  = (float*)alloc((size_t)LL * 256 * 4);
  float* pooled = (float*)alloc((size_t)GG * 512 * 4);
  size_t zero_bytes = off;
  // rest
  float* A      = (float*)alloc((size_t)NN * FF * 4);
  float* Bh     = (float*)alloc((size_t)NN * FF * 4);
  int*   csrc   = (int*)alloc((size_t)EE * 4);
  float* cw     = (float*)alloc((size_t)EE * 4);
  float* dinv   = (float*)alloc((size_t)NN * 4);
  int*   rowptr = (int*)alloc((size_t)(NN + 1) * 4);
  int*   gstart = (int*)alloc((size_t)(GG + 1) * 4);
  float* z1     = (float*)alloc((size_t)GG * FF * 4);
  float* bnsc   = (float*)alloc(256 * 4);
  float* zsc    = (float*)alloc(256 * 4);
  (void)ws_size; (void)in_sizes; (void)n_in; (void)out_size;

  hipMemsetAsync(d_ws, 0, zero_bytes, stream);

  k_deg<<<(EE + 255) / 256, 256, 0, stream>>>(ei + EE, deg);
  k_dinv<<<(NN + 255) / 256, 256, 0, stream>>>(deg, dinv);
  k_scan<<<1, 1024, 0, stream>>>(deg, rowptr);
  k_fill<<<(EE + 255) / 256, 256, 0, stream>>>(ei, rowptr, cnt, dinv, csrc, cw);
  k_bounds<<<(NN + 255) / 256, 256, 0, stream>>>(batch, gstart);

  for (int t = 0; t < LL; ++t) {
    const float* hin = (t == 0) ? x : A;
    k_gemm<<<(NN + 63) / 64, 256, 0, stream>>>(hin, Ws + (size_t)t * FF * FF, Bh);
    k_agg<<<2048, 256, 0, stream>>>(Bh, rowptr, csrc, cw, bs + t * FF, A, bnbuf + t * 256);
    k_bnfin<<<1, 128, 0, stream>>>(bnbuf + t * 256, gammas + t * FF, betas + t * FF, bnsc);
    k_bnapply<<<GG * 8, 128, 0, stream>>>(A, bnsc, gstart, pooled + t * FF);
  }

  k_z1<<<GG, 128, 0, stream>>>(pooled, W1, b1, z1);
  k_zstat<<<1, 128, 0, stream>>>(z1, g1, bt1, zsc);
  k_out<<<GG, 128, 0, stream>>>(z1, zsc, W2, b2, out);
}

// Round 2
// 1355.832 us; speedup vs baseline: 1.1068x; 1.1068x over previous
//
#include <hip/hip_runtime.h>

#define NN 100000
#define EE 1600000
#define FF 128
#define LL 4
#define GG 512
#define OUTC 10
#define EPSF 1e-5f

// ---------- graph setup ----------

__global__ __launch_bounds__(256) void k_deg(const int* __restrict__ col, int* __restrict__ deg) {
  int e = blockIdx.x * 256 + threadIdx.x;
  if (e < EE) atomicAdd(&deg[col[e]], 1);
}

__global__ __launch_bounds__(256) void k_dinv(const int* __restrict__ deg, float* __restrict__ dinv) {
  int n = blockIdx.x * 256 + threadIdx.x;
  if (n < NN) {
    int d = deg[n];
    dinv[n] = d > 0 ? rsqrtf((float)d) : 0.0f;
  }
}

// single-block exclusive scan of deg -> rowptr[0..NN]
__global__ __launch_bounds__(1024) void k_scan(const int* __restrict__ deg, int* __restrict__ rowptr) {
  __shared__ int ssum[1024];
  const int t = threadIdx.x;
  const int CH = (NN + 1023) / 1024;  // 98
  const int s = t * CH;
  const int e = min(s + CH, NN);
  int local = 0;
  for (int i = s; i < e; ++i) local += deg[i];
  ssum[t] = local;
  __syncthreads();
  for (int off = 1; off < 1024; off <<= 1) {
    int v = (t >= off) ? ssum[t - off] : 0;
    __syncthreads();
    ssum[t] += v;
    __syncthreads();
  }
  int base = (t == 0) ? 0 : ssum[t - 1];
  for (int i = s; i < e; ++i) {
    rowptr[i] = base;
    base += deg[i];
  }
  if (t == 1023) rowptr[NN] = ssum[1023];
}

__global__ __launch_bounds__(256) void k_fill(const int* __restrict__ ei,
                                              const int* __restrict__ rowptr,
                                              int* __restrict__ cnt,
                                              const float* __restrict__ dinv,
                                              int* __restrict__ csrc,
                                              float* __restrict__ cw) {
  int e = blockIdx.x * 256 + threadIdx.x;
  if (e >= EE) return;
  int r = ei[e];
  int cl = ei[EE + e];
  int slot = rowptr[cl] + atomicAdd(&cnt[cl], 1);
  csrc[slot] = r;
  cw[slot] = dinv[r] * dinv[cl];
}

// batch is sorted: gstart[g] = first node of graph g; gstart[GG] = NN
__global__ __launch_bounds__(256) void k_bounds(const int* __restrict__ batch, int* __restrict__ gstart) {
  int n = blockIdx.x * 256 + threadIdx.x;
  if (n >= NN) return;
  int b = batch[n];
  if (n == 0) {
    for (int g = 0; g <= b; ++g) gstart[g] = 0;
  } else {
    int bp = batch[n - 1];
    for (int g = bp + 1; g <= b; ++g) gstart[g] = n;
  }
  if (n == NN - 1) {
    for (int g = b + 1; g <= GG; ++g) gstart[g] = NN;
  }
}

// ---------- per-layer GEMM: C[N,128] = A[N,128] @ W[128,128] ----------
__global__ __launch_bounds__(256) void k_gemm(const float* __restrict__ A,
                                              const float* __restrict__ W,
                                              float* __restrict__ C) {
  __shared__ float sA[64 * 65];   // padded leading dim
  __shared__ float sW[64 * 128];
  const int tid = threadIdx.x;
  const int tx = tid & 15;
  const int ty = tid >> 4;
  const int tx8 = tx * 8;
  const int ty4 = ty * 4;
  const int rowbase = blockIdx.x * 64;

  float acc[4][8];
#pragma unroll
  for (int i = 0; i < 4; ++i)
#pragma unroll
    for (int j = 0; j < 8; ++j) acc[i][j] = 0.0f;

  for (int kc = 0; kc < 128; kc += 64) {
#pragma unroll
    for (int i = 0; i < 4; ++i) {
      int li = tid + i * 256;
      int r = li >> 4;
      int k4 = (li & 15) << 2;
      float4 v = make_float4(0.f, 0.f, 0.f, 0.f);
      int gr = rowbase + r;
      if (gr < NN) v = *(const float4*)(A + (size_t)gr * FF + kc + k4);
      sA[r * 65 + k4 + 0] = v.x;
      sA[r * 65 + k4 + 1] = v.y;
      sA[r * 65 + k4 + 2] = v.z;
      sA[r * 65 + k4 + 3] = v.w;
    }
#pragma unroll
    for (int i = 0; i < 8; ++i) {
      int li = tid + i * 256;
      int kk = li >> 5;
      int c4 = (li & 31) << 2;
      *(float4*)(sW + kk * 128 + c4) = *(const float4*)(W + (size_t)(kc + kk) * 128 + c4);
    }
    __syncthreads();
#pragma unroll 8
    for (int kk = 0; kk < 64; ++kk) {
      float av[4];
      av[0] = sA[(ty4 + 0) * 65 + kk];
      av[1] = sA[(ty4 + 1) * 65 + kk];
      av[2] = sA[(ty4 + 2) * 65 + kk];
      av[3] = sA[(ty4 + 3) * 65 + kk];
      float4 w0 = *(const float4*)(sW + kk * 128 + tx8);
      float4 w1 = *(const float4*)(sW + kk * 128 + tx8 + 4);
      float wv[8] = {w0.x, w0.y, w0.z, w0.w, w1.x, w1.y, w1.z, w1.w};
#pragma unroll
      for (int i = 0; i < 4; ++i)
#pragma unroll
        for (int j = 0; j < 8; ++j) acc[i][j] = fmaf(av[i], wv[j], acc[i][j]);
    }
    __syncthreads();
  }
#pragma unroll
  for (int i = 0; i < 4; ++i) {
    int gr = rowbase + ty4 + i;
    if (gr < NN) {
      float4 o0 = make_float4(acc[i][0], acc[i][1], acc[i][2], acc[i][3]);
      float4 o1 = make_float4(acc[i][4], acc[i][5], acc[i][6], acc[i][7]);
      *(float4*)(C + (size_t)gr * FF + tx8) = o0;
      *(float4*)(C + (size_t)gr * FF + tx8 + 4) = o1;
    }
  }
}

// ---------- aggregation: A[n] = relu(sum_e w*B[src] + bias), BN partials ----------
// one wave per node (grid-stride); lane handles channels 2*lane, 2*lane+1.
// MLP: preload 64-edge chunks cooperatively, shfl-broadcast, 4x unrolled gather
// into 4 independent accumulator pairs (4 row loads in flight per wave).
__global__ __launch_bounds__(256) void k_agg(const float* __restrict__ B,
                                             const int* __restrict__ rowptr,
                                             const int* __restrict__ csrc,
                                             const float* __restrict__ cw,
                                             const float* __restrict__ bias,
                                             float* __restrict__ Aout,
                                             float* __restrict__ bnbuf) {
  const int lane = threadIdx.x & 63;
  const int wave = threadIdx.x >> 6;
  const int c = lane * 2;
  const int gwave = blockIdx.x * 4 + wave;
  const int nwaves = gridDim.x * 4;
  const float2 bv = *(const float2*)(bias + c);
  float s0 = 0.f, s1 = 0.f, q0 = 0.f, q1 = 0.f;
  for (int n = gwave; n < NN; n += nwaves) {
    const int beg = rowptr[n];
    const int end = rowptr[n + 1];
    float a0x = 0.f, a0y = 0.f, a1x = 0.f, a1y = 0.f;
    float a2x = 0.f, a2y = 0.f, a3x = 0.f, a3y = 0.f;
    for (int base = beg; base < end; base += 64) {
      const int cntc = min(64, end - base);
      const int myj = base + lane;
      int msrc = 0;
      float mw = 0.f;
      if (myj < end) {
        msrc = csrc[myj];
        mw = cw[myj];
      }
      int k = 0;
      for (; k + 4 <= cntc; k += 4) {
        const int i0 = __shfl(msrc, k);
        const int i1 = __shfl(msrc, k + 1);
        const int i2 = __shfl(msrc, k + 2);
        const int i3 = __shfl(msrc, k + 3);
        const float w0 = __shfl(mw, k);
        const float w1 = __shfl(mw, k + 1);
        const float w2 = __shfl(mw, k + 2);
        const float w3 = __shfl(mw, k + 3);
        const float2 v0 = *(const float2*)(B + (size_t)i0 * FF + c);
        const float2 v1 = *(const float2*)(B + (size_t)i1 * FF + c);
        const float2 v2 = *(const float2*)(B + (size_t)i2 * FF + c);
        const float2 v3 = *(const float2*)(B + (size_t)i3 * FF + c);
        a0x = fmaf(w0, v0.x, a0x); a0y = fmaf(w0, v0.y, a0y);
        a1x = fmaf(w1, v1.x, a1x); a1y = fmaf(w1, v1.y, a1y);
        a2x = fmaf(w2, v2.x, a2x); a2y = fmaf(w2, v2.y, a2y);
        a3x = fmaf(w3, v3.x, a3x); a3y = fmaf(w3, v3.y, a3y);
      }
      for (; k < cntc; ++k) {
        const int i0 = __shfl(msrc, k);
        const float w0 = __shfl(mw, k);
        const float2 v0 = *(const float2*)(B + (size_t)i0 * FF + c);
        a0x = fmaf(w0, v0.x, a0x); a0y = fmaf(w0, v0.y, a0y);
      }
    }
    float ax = (a0x + a1x) + (a2x + a3x);
    float ay = (a0y + a1y) + (a2y + a3y);
    ax = fmaxf(ax + bv.x, 0.f);
    ay = fmaxf(ay + bv.y, 0.f);
    *(float2*)(Aout + (size_t)n * FF + c) = make_float2(ax, ay);
    s0 += ax; s1 += ay;
    q0 = fmaf(ax, ax, q0); q1 = fmaf(ay, ay, q1);
  }
  __shared__ float sred[4][256];
  sred[wave][c] = s0;
  sred[wave][c + 1] = s1;
  sred[wave][128 + c] = q0;
  sred[wave][128 + c + 1] = q1;
  __syncthreads();
  const int t = threadIdx.x;
  float tot = sred[0][t] + sred[1][t] + sred[2][t] + sred[3][t];
  atomicAdd(&bnbuf[t], tot);
}

__global__ __launch_bounds__(128) void k_bnfin(const float* __restrict__ bnbuf,
                                               const float* __restrict__ gamma,
                                               const float* __restrict__ beta,
                                               float* __restrict__ bnsc) {
  const int c = threadIdx.x;
  float mu = bnbuf[c] * (1.0f / NN);
  float var = bnbuf[128 + c] * (1.0f / NN) - mu * mu;
  float inv = rsqrtf(var + EPSF);
  float sc = gamma[c] * inv;
  bnsc[c] = sc;
  bnsc[128 + c] = beta[c] - mu * sc;
}

// BN apply in-place + pooled (graph-sorted, 8 blocks per graph, 1 atomic/channel/block)
__global__ __launch_bounds__(128) void k_bnapply(float* __restrict__ A,
                                                 const float* __restrict__ bnsc,
                                                 const int* __restrict__ gstart,
                                                 float* __restrict__ pooledt) {
  const int g = blockIdx.x >> 3;
  const int sub = blockIdx.x & 7;
  const int s = gstart[g];
  const int e = gstart[g + 1];
  const int cnt = e - s;
  if (cnt <= 0) return;
  const int per = (cnt + 7) >> 3;
  const int ns = s + sub * per;
  const int ne = min(ns + per, e);
  if (ns >= ne) return;
  const int c = threadIdx.x;
  const float sc = bnsc[c];
  const float sh = bnsc[128 + c];
  float acc = 0.f;
  for (int n = ns; n < ne; ++n) {
    float v = fmaf(A[(size_t)n * FF + c], sc, sh);
    A[(size_t)n * FF + c] = v;
    acc += v;
  }
  atomicAdd(&pooledt[(size_t)g * 512 + c], acc);
}

// ---------- head ----------

__global__ __launch_bounds__(128) void k_z1(const float* __restrict__ pooled,
                                            const float* __restrict__ W1,
                                            const float* __restrict__ b1,
                                            float* __restrict__ z1) {
  __shared__ float sp[512];
  const int g = blockIdx.x;
  for (int i = threadIdx.x; i < 512; i += 128) sp[i] = pooled[(size_t)g * 512 + i];
  __syncthreads();
  const int c = threadIdx.x;
  float acc = b1[c];
  for (int j = 0; j < 512; ++j) acc = fmaf(sp[j], W1[j * 128 + c], acc);
  z1[(size_t)g * 128 + c] = acc;
}

__global__ __launch_bounds__(128) void k_zstat(const float* __restrict__ z1,
                                               const float* __restrict__ g1,
                                               const float* __restrict__ bt1,
                                               float* __restrict__ zsc) {
  const int c = threadIdx.x;
  float s = 0.f, q = 0.f;
  for (int g = 0; g < GG; ++g) {
    float v = z1[g * 128 + c];
    s += v;
    q = fmaf(v, v, q);
  }
  float mu = s * (1.0f / GG);
  float var = q * (1.0f / GG) - mu * mu;
  float inv = rsqrtf(var + EPSF);
  float sc = g1[c] * inv;
  zsc[c] = sc;
  zsc[128 + c] = bt1[c] - mu * sc;
}

__global__ __launch_bounds__(128) void k_out(const float* __restrict__ z1,
                                             const float* __restrict__ zsc,
                                             const float* __restrict__ W2,
                                             const float* __restrict__ b2,
                                             float* __restrict__ out) {
  __shared__ float zr[128];
  const int g = blockIdx.x;
  const int c = threadIdx.x;
  zr[c] = fmaxf(fmaf(z1[(size_t)g * 128 + c], zsc[c], zsc[128 + c]), 0.f);
  __syncthreads();
  if (c < OUTC) {
    float acc = b2[c];
    for (int k = 0; k < 128; ++k) acc = fmaf(zr[k], W2[k * OUTC + c], acc);
    out[(size_t)g * OUTC + c] = acc;
  }
}

// ---------- launch ----------

extern "C" void kernel_launch(void* const* d_in, const int* in_sizes, int n_in,
                              void* d_out, int out_size, void* d_ws, size_t ws_size,
                              hipStream_t stream) {
  const float* x      = (const float*)d_in[0];
  const int*   ei     = (const int*)d_in[1];
  const int*   batch  = (const int*)d_in[2];
  const float* Ws     = (const float*)d_in[3];
  const float* bs     = (const float*)d_in[4];
  const float* gammas = (const float*)d_in[5];
  const float* betas  = (const float*)d_in[6];
  const float* W1     = (const float*)d_in[7];
  const float* b1     = (const float*)d_in[8];
  const float* g1     = (const float*)d_in[9];
  const float* bt1    = (const float*)d_in[10];
  const float* W2     = (const float*)d_in[11];
  const float* b2     = (const float*)d_in[12];
  float* out = (float*)d_out;

  char* ws = (char*)d_ws;
  size_t off = 0;
  auto alloc = [&](size_t bytes) -> void* {
    void* p = ws + off;
    off = (off + bytes + 255) & ~(size_t)255;
    return p;
  };
  // zero-initialized region (single memset)
  int*   deg    = (int*)alloc((size_t)NN * 4);
  int*   cnt    = (int*)alloc((size_t)NN * 4);
  float* bnbuf  = (float*)alloc((size_t)LL * 256 * 4);
  float* pooled = (float*)alloc((size_t)GG * 512 * 4);
  size_t zero_bytes = off;
  // rest
  float* A      = (float*)alloc((size_t)NN * FF * 4);
  float* Bh     = (float*)alloc((size_t)NN * FF * 4);
  int*   csrc   = (int*)alloc((size_t)EE * 4);
  float* cw     = (float*)alloc((size_t)EE * 4);
  float* dinv   = (float*)alloc((size_t)NN * 4);
  int*   rowptr = (int*)alloc((size_t)(NN + 1) * 4);
  int*   gstart = (int*)alloc((size_t)(GG + 1) * 4);
  float* z1     = (float*)alloc((size_t)GG * FF * 4);
  float* bnsc   = (float*)alloc(256 * 4);
  float* zsc    = (float*)alloc(256 * 4);
  (void)ws_size; (void)in_sizes; (void)n_in; (void)out_size;

  hipMemsetAsync(d_ws, 0, zero_bytes, stream);

  k_deg<<<(EE + 255) / 256, 256, 0, stream>>>(ei + EE, deg);
  k_dinv<<<(NN + 255) / 256, 256, 0, stream>>>(deg, dinv);
  k_scan<<<1, 1024, 0, stream>>>(deg, rowptr);
  k_fill<<<(EE + 255) / 256, 256, 0, stream>>>(ei, rowptr, cnt, dinv, csrc, cw);
  k_bounds<<<(NN + 255) / 256, 256, 0, stream>>>(batch, gstart);

  for (int t = 0; t < LL; ++t) {
    const float* hin = (t == 0) ? x : A;
    k_gemm<<<(NN + 63) / 64, 256, 0, stream>>>(hin, Ws + (size_t)t * FF * FF, Bh);
    k_agg<<<2048, 256, 0, stream>>>(Bh, rowptr, csrc, cw, bs + t * FF, A, bnbuf + t * 256);
    k_bnfin<<<1, 128, 0, stream>>>(bnbuf + t * 256, gammas + t * FF, betas + t * FF, bnsc);
    k_bnapply<<<GG * 8, 128, 0, stream>>>(A, bnsc, gstart, pooled + t * FF);
  }

  k_z1<<<GG, 128, 0, stream>>>(pooled, W1, b1, z1);
  k_zstat<<<1, 128, 0, stream>>>(z1, g1, bt1, zsc);
  k_out<<<GG, 128, 0, stream>>>(z1, zsc, W2, b2, out);
}

// Round 3
// 1200.413 us; speedup vs baseline: 1.2501x; 1.1295x over previous
//
#include <hip/hip_runtime.h>

#define NN 100000
#define EE 1600000
#define FF 128
#define LL 4
#define GG 512
#define OUTC 10
#define EPSF 1e-5f
#define NSCB ((NN + 255) / 256)   // 391 scan blocks

// ---------- graph setup ----------

__global__ __launch_bounds__(256) void k_deg(const int* __restrict__ col, int* __restrict__ deg) {
  int e = blockIdx.x * 256 + threadIdx.x;
  if (e < EE) atomicAdd(&deg[col[e]], 1);
}

__global__ __launch_bounds__(256) void k_dinv(const int* __restrict__ deg, float* __restrict__ dinv) {
  int n = blockIdx.x * 256 + threadIdx.x;
  if (n < NN) {
    int d = deg[n];
    dinv[n] = d > 0 ? rsqrtf((float)d) : 0.0f;
  }
}

// per-block degree sums (391 blocks x 256)
__global__ __launch_bounds__(256) void k_bsum(const int* __restrict__ deg, int* __restrict__ bsum) {
  int i = blockIdx.x * 256 + threadIdx.x;
  int v = (i < NN) ? deg[i] : 0;
#pragma unroll
  for (int off = 32; off > 0; off >>= 1) v += __shfl_down(v, off, 64);
  __shared__ int ws[4];
  if ((threadIdx.x & 63) == 0) ws[threadIdx.x >> 6] = v;
  __syncthreads();
  if (threadIdx.x == 0) bsum[blockIdx.x] = ws[0] + ws[1] + ws[2] + ws[3];
}

// each block: scan all block sums in LDS (redundant), local scan of its 256 degs,
// write exclusive rowptr. rowptr[NN] = EE (constant).
__global__ __launch_bounds__(256) void k_rowptr(const int* __restrict__ deg,
                                                const int* __restrict__ bsum,
                                                int* __restrict__ rowptr) {
  __shared__ int sb[512];
  __shared__ int sd[256];
  const int t = threadIdx.x;
  sb[t]       = (t < NSCB) ? bsum[t] : 0;
  sb[t + 256] = (t + 256 < NSCB) ? bsum[t + 256] : 0;
  __syncthreads();
#pragma unroll
  for (int off = 1; off < 512; off <<= 1) {
    int v0 = (t >= off) ? sb[t - off] : 0;
    int v1 = sb[t + 256 - off];
    __syncthreads();
    sb[t] += v0;
    sb[t + 256] += v1;
    __syncthreads();
  }
  const int bpre = (blockIdx.x == 0) ? 0 : sb[blockIdx.x - 1];
  const int i = blockIdx.x * 256 + t;
  const int d = (i < NN) ? deg[i] : 0;
  sd[t] = d;
  __syncthreads();
#pragma unroll
  for (int off = 1; off < 256; off <<= 1) {
    int v = (t >= off) ? sd[t - off] : 0;
    __syncthreads();
    sd[t] += v;
    __syncthreads();
  }
  if (i < NN) rowptr[i] = bpre + sd[t] - d;
  if (blockIdx.x == 0 && t == 0) rowptr[NN] = EE;
}

__global__ __launch_bounds__(256) void k_fill(const int* __restrict__ ei,
                                              const int* __restrict__ rowptr,
                                              int* __restrict__ cnt,
                                              const float* __restrict__ dinv,
                                              int* __restrict__ csrc,
                                              float* __restrict__ cw) {
  int e = blockIdx.x * 256 + threadIdx.x;
  if (e >= EE) return;
  int r = ei[e];
  int cl = ei[EE + e];
  int slot = rowptr[cl] + atomicAdd(&cnt[cl], 1);
  csrc[slot] = r;
  cw[slot] = dinv[r] * dinv[cl];
}

// batch is sorted: gstart[g] = first node of graph g; gstart[GG] = NN
__global__ __launch_bounds__(256) void k_bounds(const int* __restrict__ batch, int* __restrict__ gstart) {
  int n = blockIdx.x * 256 + threadIdx.x;
  if (n >= NN) return;
  int b = batch[n];
  if (n == 0) {
    for (int g = 0; g <= b; ++g) gstart[g] = 0;
  } else {
    int bp = batch[n - 1];
    for (int g = bp + 1; g <= b; ++g) gstart[g] = n;
  }
  if (n == NN - 1) {
    for (int g = b + 1; g <= GG; ++g) gstart[g] = NN;
  }
}

// ---------- per-layer GEMM: C[N,128] = A[N,128] @ W[128,128] ----------
__global__ __launch_bounds__(256) void k_gemm(const float* __restrict__ A,
                                              const float* __restrict__ W,
                                              float* __restrict__ C) {
  __shared__ float sA[64 * 65];   // padded leading dim
  __shared__ float sW[64 * 128];
  const int tid = threadIdx.x;
  const int tx = tid & 15;
  const int ty = tid >> 4;
  const int tx8 = tx * 8;
  const int ty4 = ty * 4;
  const int rowbase = blockIdx.x * 64;

  float acc[4][8];
#pragma unroll
  for (int i = 0; i < 4; ++i)
#pragma unroll
    for (int j = 0; j < 8; ++j) acc[i][j] = 0.0f;

  for (int kc = 0; kc < 128; kc += 64) {
#pragma unroll
    for (int i = 0; i < 4; ++i) {
      int li = tid + i * 256;
      int r = li >> 4;
      int k4 = (li & 15) << 2;
      float4 v = make_float4(0.f, 0.f, 0.f, 0.f);
      int gr = rowbase + r;
      if (gr < NN) v = *(const float4*)(A + (size_t)gr * FF + kc + k4);
      sA[r * 65 + k4 + 0] = v.x;
      sA[r * 65 + k4 + 1] = v.y;
      sA[r * 65 + k4 + 2] = v.z;
      sA[r * 65 + k4 + 3] = v.w;
    }
#pragma unroll
    for (int i = 0; i < 8; ++i) {
      int li = tid + i * 256;
      int kk = li >> 5;
      int c4 = (li & 31) << 2;
      *(float4*)(sW + kk * 128 + c4) = *(const float4*)(W + (size_t)(kc + kk) * 128 + c4);
    }
    __syncthreads();
#pragma unroll 8
    for (int kk = 0; kk < 64; ++kk) {
      float av[4];
      av[0] = sA[(ty4 + 0) * 65 + kk];
      av[1] = sA[(ty4 + 1) * 65 + kk];
      av[2] = sA[(ty4 + 2) * 65 + kk];
      av[3] = sA[(ty4 + 3) * 65 + kk];
      float4 w0 = *(const float4*)(sW + kk * 128 + tx8);
      float4 w1 = *(const float4*)(sW + kk * 128 + tx8 + 4);
      float wv[8] = {w0.x, w0.y, w0.z, w0.w, w1.x, w1.y, w1.z, w1.w};
#pragma unroll
      for (int i = 0; i < 4; ++i)
#pragma unroll
        for (int j = 0; j < 8; ++j) acc[i][j] = fmaf(av[i], wv[j], acc[i][j]);
    }
    __syncthreads();
  }
#pragma unroll
  for (int i = 0; i < 4; ++i) {
    int gr = rowbase + ty4 + i;
    if (gr < NN) {
      float4 o0 = make_float4(acc[i][0], acc[i][1], acc[i][2], acc[i][3]);
      float4 o1 = make_float4(acc[i][4], acc[i][5], acc[i][6], acc[i][7]);
      *(float4*)(C + (size_t)gr * FF + tx8) = o0;
      *(float4*)(C + (size_t)gr * FF + tx8 + 4) = o1;
    }
  }
}

// ---------- aggregation: A[n] = relu(sum_e w*B[src] + bias), BN partials ----------
__global__ __launch_bounds__(256) void k_agg(const float* __restrict__ B,
                                             const int* __restrict__ rowptr,
                                             const int* __restrict__ csrc,
                                             const float* __restrict__ cw,
                                             const float* __restrict__ bias,
                                             float* __restrict__ Aout,
                                             float* __restrict__ bnbuf) {
  const int lane = threadIdx.x & 63;
  const int wave = threadIdx.x >> 6;
  const int c = lane * 2;
  const int gwave = blockIdx.x * 4 + wave;
  const int nwaves = gridDim.x * 4;
  const float2 bv = *(const float2*)(bias + c);
  float s0 = 0.f, s1 = 0.f, q0 = 0.f, q1 = 0.f;
  for (int n = gwave; n < NN; n += nwaves) {
    const int beg = rowptr[n];
    const int end = rowptr[n + 1];
    float a0x = 0.f, a0y = 0.f, a1x = 0.f, a1y = 0.f;
    float a2x = 0.f, a2y = 0.f, a3x = 0.f, a3y = 0.f;
    for (int base = beg; base < end; base += 64) {
      const int cntc = min(64, end - base);
      const int myj = base + lane;
      int msrc = 0;
      float mw = 0.f;
      if (myj < end) {
        msrc = csrc[myj];
        mw = cw[myj];
      }
      int k = 0;
      for (; k + 4 <= cntc; k += 4) {
        const int i0 = __shfl(msrc, k);
        const int i1 = __shfl(msrc, k + 1);
        const int i2 = __shfl(msrc, k + 2);
        const int i3 = __shfl(msrc, k + 3);
        const float w0 = __shfl(mw, k);
        const float w1 = __shfl(mw, k + 1);
        const float w2 = __shfl(mw, k + 2);
        const float w3 = __shfl(mw, k + 3);
        const float2 v0 = *(const float2*)(B + (size_t)i0 * FF + c);
        const float2 v1 = *(const float2*)(B + (size_t)i1 * FF + c);
        const float2 v2 = *(const float2*)(B + (size_t)i2 * FF + c);
        const float2 v3 = *(const float2*)(B + (size_t)i3 * FF + c);
        a0x = fmaf(w0, v0.x, a0x); a0y = fmaf(w0, v0.y, a0y);
        a1x = fmaf(w1, v1.x, a1x); a1y = fmaf(w1, v1.y, a1y);
        a2x = fmaf(w2, v2.x, a2x); a2y = fmaf(w2, v2.y, a2y);
        a3x = fmaf(w3, v3.x, a3x); a3y = fmaf(w3, v3.y, a3y);
      }
      for (; k < cntc; ++k) {
        const int i0 = __shfl(msrc, k);
        const float w0 = __shfl(mw, k);
        const float2 v0 = *(const float2*)(B + (size_t)i0 * FF + c);
        a0x = fmaf(w0, v0.x, a0x); a0y = fmaf(w0, v0.y, a0y);
      }
    }
    float ax = (a0x + a1x) + (a2x + a3x);
    float ay = (a0y + a1y) + (a2y + a3y);
    ax = fmaxf(ax + bv.x, 0.f);
    ay = fmaxf(ay + bv.y, 0.f);
    *(float2*)(Aout + (size_t)n * FF + c) = make_float2(ax, ay);
    s0 += ax; s1 += ay;
    q0 = fmaf(ax, ax, q0); q1 = fmaf(ay, ay, q1);
  }
  __shared__ float sred[4][256];
  sred[wave][c] = s0;
  sred[wave][c + 1] = s1;
  sred[wave][128 + c] = q0;
  sred[wave][128 + c + 1] = q1;
  __syncthreads();
  const int t = threadIdx.x;
  float tot = sred[0][t] + sred[1][t] + sred[2][t] + sred[3][t];
  atomicAdd(&bnbuf[t], tot);
}

__global__ __launch_bounds__(128) void k_bnfin(const float* __restrict__ bnbuf,
                                               const float* __restrict__ gamma,
                                               const float* __restrict__ beta,
                                               float* __restrict__ bnsc) {
  const int c = threadIdx.x;
  float mu = bnbuf[c] * (1.0f / NN);
  float var = bnbuf[128 + c] * (1.0f / NN) - mu * mu;
  float inv = rsqrtf(var + EPSF);
  float sc = gamma[c] * inv;
  bnsc[c] = sc;
  bnsc[128 + c] = beta[c] - mu * sc;
}

// BN apply in-place + pooled (graph-sorted, 8 blocks per graph, 1 atomic/channel/block)
__global__ __launch_bounds__(128) void k_bnapply(float* __restrict__ A,
                                                 const float* __restrict__ bnsc,
                                                 const int* __restrict__ gstart,
                                                 float* __restrict__ pooledt) {
  const int g = blockIdx.x >> 3;
  const int sub = blockIdx.x & 7;
  const int s = gstart[g];
  const int e = gstart[g + 1];
  const int cnt = e - s;
  if (cnt <= 0) return;
  const int per = (cnt + 7) >> 3;
  const int ns = s + sub * per;
  const int ne = min(ns + per, e);
  if (ns >= ne) return;
  const int c = threadIdx.x;
  const float sc = bnsc[c];
  const float sh = bnsc[128 + c];
  float acc = 0.f;
  for (int n = ns; n < ne; ++n) {
    float v = fmaf(A[(size_t)n * FF + c], sc, sh);
    A[(size_t)n * FF + c] = v;
    acc += v;
  }
  atomicAdd(&pooledt[(size_t)g * 512 + c], acc);
}

// ---------- head ----------

__global__ __launch_bounds__(128) void k_z1(const float* __restrict__ pooled,
                                            const float* __restrict__ W1,
                                            const float* __restrict__ b1,
                                            float* __restrict__ z1) {
  __shared__ float sp[512];
  const int g = blockIdx.x;
  for (int i = threadIdx.x; i < 512; i += 128) sp[i] = pooled[(size_t)g * 512 + i];
  __syncthreads();
  const int c = threadIdx.x;
  float acc = b1[c];
  for (int j = 0; j < 512; ++j) acc = fmaf(sp[j], W1[j * 128 + c], acc);
  z1[(size_t)g * 128 + c] = acc;
}

__global__ __launch_bounds__(128) void k_zstat(const float* __restrict__ z1,
                                               const float* __restrict__ g1,
                                               const float* __restrict__ bt1,
                                               float* __restrict__ zsc) {
  const int c = threadIdx.x;
  float s = 0.f, q = 0.f;
  for (int g = 0; g < GG; ++g) {
    float v = z1[g * 128 + c];
    s += v;
    q = fmaf(v, v, q);
  }
  float mu = s * (1.0f / GG);
  float var = q * (1.0f / GG) - mu * mu;
  float inv = rsqrtf(var + EPSF);
  float sc = g1[c] * inv;
  zsc[c] = sc;
  zsc[128 + c] = bt1[c] - mu * sc;
}

__global__ __launch_bounds__(128) void k_out(const float* __restrict__ z1,
                                             const float* __restrict__ zsc,
                                             const float* __restrict__ W2,
                                             const float* __restrict__ b2,
                                             float* __restrict__ out) {
  __shared__ float zr[128];
  const int g = blockIdx.x;
  const int c = threadIdx.x;
  zr[c] = fmaxf(fmaf(z1[(size_t)g * 128 + c], zsc[c], zsc[128 + c]), 0.f);
  __syncthreads();
  if (c < OUTC) {
    float acc = b2[c];
    for (int k = 0; k < 128; ++k) acc = fmaf(zr[k], W2[k * OUTC + c], acc);
    out[(size_t)g * OUTC + c] = acc;
  }
}

// ---------- launch ----------

extern "C" void kernel_launch(void* const* d_in, const int* in_sizes, int n_in,
                              void* d_out, int out_size, void* d_ws, size_t ws_size,
                              hipStream_t stream) {
  const float* x      = (const float*)d_in[0];
  const int*   ei     = (const int*)d_in[1];
  const int*   batch  = (const int*)d_in[2];
  const float* Ws     = (const float*)d_in[3];
  const float* bs     = (const float*)d_in[4];
  const float* gammas = (const float*)d_in[5];
  const float* betas  = (const float*)d_in[6];
  const float* W1     = (const float*)d_in[7];
  const float* b1     = (const float*)d_in[8];
  const float* g1     = (const float*)d_in[9];
  const float* bt1    = (const float*)d_in[10];
  const float* W2     = (const float*)d_in[11];
  const float* b2     = (const float*)d_in[12];
  float* out = (float*)d_out;

  char* ws = (char*)d_ws;
  size_t off = 0;
  auto alloc = [&](size_t bytes) -> void* {
    void* p = ws + off;
    off = (off + bytes + 255) & ~(size_t)255;
    return p;
  };
  // zero-initialized region (single memset)
  int*   deg    = (int*)alloc((size_t)NN * 4);
  int*   cnt    = (int*)alloc((size_t)NN * 4);
  float* bnbuf  = (float*)alloc((size_t)LL * 256 * 4);
  float* pooled = (float*)alloc((size_t)GG * 512 * 4);
  size_t zero_bytes = off;
  // rest
  float* A      = (float*)alloc((size_t)NN * FF * 4);
  float* Bh     = (float*)alloc((size_t)NN * FF * 4);
  int*   csrc   = (int*)alloc((size_t)EE * 4);
  float* cw     = (float*)alloc((size_t)EE * 4);
  float* dinv   = (float*)alloc((size_t)NN * 4);
  int*   rowptr = (int*)alloc((size_t)(NN + 1) * 4);
  int*   bsum   = (int*)alloc((size_t)NSCB * 4);
  int*   gstart = (int*)alloc((size_t)(GG + 1) * 4);
  float* z1     = (float*)alloc((size_t)GG * FF * 4);
  float* bnsc   = (float*)alloc(256 * 4);
  float* zsc    = (float*)alloc(256 * 4);
  (void)ws_size; (void)in_sizes; (void)n_in; (void)out_size;

  hipMemsetAsync(d_ws, 0, zero_bytes, stream);

  k_deg<<<(EE + 255) / 256, 256, 0, stream>>>(ei + EE, deg);
  k_dinv<<<(NN + 255) / 256, 256, 0, stream>>>(deg, dinv);
  k_bsum<<<NSCB, 256, 0, stream>>>(deg, bsum);
  k_rowptr<<<NSCB, 256, 0, stream>>>(deg, bsum, rowptr);
  k_fill<<<(EE + 255) / 256, 256, 0, stream>>>(ei, rowptr, cnt, dinv, csrc, cw);
  k_bounds<<<(NN + 255) / 256, 256, 0, stream>>>(batch, gstart);

  for (int t = 0; t < LL; ++t) {
    const float* hin = (t == 0) ? x : A;
    k_gemm<<<(NN + 63) / 64, 256, 0, stream>>>(hin, Ws + (size_t)t * FF * FF, Bh);
    k_agg<<<2048, 256, 0, stream>>>(Bh, rowptr, csrc, cw, bs + t * FF, A, bnbuf + t * 256);
    k_bnfin<<<1, 128, 0, stream>>>(bnbuf + t * 256, gammas + t * FF, betas + t * FF, bnsc);
    k_bnapply<<<GG * 8, 128, 0, stream>>>(A, bnsc, gstart, pooled + t * FF);
  }

  k_z1<<<GG, 128, 0, stream>>>(pooled, W1, b1, z1);
  k_zstat<<<1, 128, 0, stream>>>(z1, g1, bt1, zsc);
  k_out<<<GG, 128, 0, stream>>>(z1, zsc, W2, b2, out);
}

// Round 4
// 1003.884 us; speedup vs baseline: 1.4949x; 1.1958x over previous
//
#include <hip/hip_runtime.h>

#define NN 100000
#define EE 1600000
#define FF 128
#define LL 4
#define GG 512
#define OUTC 10
#define EPSF 1e-5f
#define NSCB ((NN + 255) / 256)   // 391 scan blocks

__device__ inline unsigned bf16rne(float f) {
  unsigned u = __float_as_uint(f);
  return (u + 0x7fffu + ((u >> 16) & 1u)) >> 16;
}
__device__ inline unsigned packbf(float lo, float hi) {
  return bf16rne(lo) | (bf16rne(hi) << 16);
}
__device__ inline float bflo(unsigned u) { return __uint_as_float(u << 16); }
__device__ inline float bfhi(unsigned u) { return __uint_as_float(u & 0xffff0000u); }

// ---------- graph setup ----------

__global__ __launch_bounds__(256) void k_deg(const int* __restrict__ col, int* __restrict__ deg) {
  int e = blockIdx.x * 256 + threadIdx.x;
  if (e < EE) atomicAdd(&deg[col[e]], 1);
}

__global__ __launch_bounds__(256) void k_dinv(const int* __restrict__ deg, float* __restrict__ dinv) {
  int n = blockIdx.x * 256 + threadIdx.x;
  if (n < NN) {
    int d = deg[n];
    dinv[n] = d > 0 ? rsqrtf((float)d) : 0.0f;
  }
}

// per-block degree sums (391 blocks x 256)
__global__ __launch_bounds__(256) void k_bsum(const int* __restrict__ deg, int* __restrict__ bsum) {
  int i = blockIdx.x * 256 + threadIdx.x;
  int v = (i < NN) ? deg[i] : 0;
#pragma unroll
  for (int off = 32; off > 0; off >>= 1) v += __shfl_down(v, off, 64);
  __shared__ int ws[4];
  if ((threadIdx.x & 63) == 0) ws[threadIdx.x >> 6] = v;
  __syncthreads();
  if (threadIdx.x == 0) bsum[blockIdx.x] = ws[0] + ws[1] + ws[2] + ws[3];
}

// each block: scan all block sums in LDS (redundant), local scan of its 256 degs,
// write exclusive rowptr. rowptr[NN] = EE (constant).
__global__ __launch_bounds__(256) void k_rowptr(const int* __restrict__ deg,
                                                const int* __restrict__ bsum,
                                                int* __restrict__ rowptr) {
  __shared__ int sb[512];
  __shared__ int sd[256];
  const int t = threadIdx.x;
  sb[t]       = (t < NSCB) ? bsum[t] : 0;
  sb[t + 256] = (t + 256 < NSCB) ? bsum[t + 256] : 0;
  __syncthreads();
#pragma unroll
  for (int off = 1; off < 512; off <<= 1) {
    int v0 = (t >= off) ? sb[t - off] : 0;
    int v1 = sb[t + 256 - off];
    __syncthreads();
    sb[t] += v0;
    sb[t + 256] += v1;
    __syncthreads();
  }
  const int bpre = (blockIdx.x == 0) ? 0 : sb[blockIdx.x - 1];
  const int i = blockIdx.x * 256 + t;
  const int d = (i < NN) ? deg[i] : 0;
  sd[t] = d;
  __syncthreads();
#pragma unroll
  for (int off = 1; off < 256; off <<= 1) {
    int v = (t >= off) ? sd[t - off] : 0;
    __syncthreads();
    sd[t] += v;
    __syncthreads();
  }
  if (i < NN) rowptr[i] = bpre + sd[t] - d;
  if (blockIdx.x == 0 && t == 0) rowptr[NN] = EE;
}

__global__ __launch_bounds__(256) void k_fill(const int* __restrict__ ei,
                                              const int* __restrict__ rowptr,
                                              int* __restrict__ cnt,
                                              const float* __restrict__ dinv,
                                              int* __restrict__ csrc,
                                              float* __restrict__ cw) {
  int e = blockIdx.x * 256 + threadIdx.x;
  if (e >= EE) return;
  int r = ei[e];
  int cl = ei[EE + e];
  int slot = rowptr[cl] + atomicAdd(&cnt[cl], 1);
  csrc[slot] = r;
  cw[slot] = dinv[r] * dinv[cl];
}

// batch is sorted: gstart[g] = first node of graph g; gstart[GG] = NN
__global__ __launch_bounds__(256) void k_bounds(const int* __restrict__ batch, int* __restrict__ gstart) {
  int n = blockIdx.x * 256 + threadIdx.x;
  if (n >= NN) return;
  int b = batch[n];
  if (n == 0) {
    for (int g = 0; g <= b; ++g) gstart[g] = 0;
  } else {
    int bp = batch[n - 1];
    for (int g = bp + 1; g <= b; ++g) gstart[g] = n;
  }
  if (n == NN - 1) {
    for (int g = b + 1; g <= GG; ++g) gstart[g] = NN;
  }
}

// ---------- per-layer GEMM: Cb[N,128](bf16 packed) = A[N,128] @ W[128,128] ----------
__global__ __launch_bounds__(256) void k_gemm(const float* __restrict__ A,
                                              const float* __restrict__ W,
                                              unsigned* __restrict__ Cb) {
  __shared__ float sA[64 * 65];   // padded leading dim
  __shared__ float sW[64 * 128];
  const int tid = threadIdx.x;
  const int tx = tid & 15;
  const int ty = tid >> 4;
  const int tx8 = tx * 8;
  const int ty4 = ty * 4;
  const int rowbase = blockIdx.x * 64;

  float acc[4][8];
#pragma unroll
  for (int i = 0; i < 4; ++i)
#pragma unroll
    for (int j = 0; j < 8; ++j) acc[i][j] = 0.0f;

  for (int kc = 0; kc < 128; kc += 64) {
#pragma unroll
    for (int i = 0; i < 4; ++i) {
      int li = tid + i * 256;
      int r = li >> 4;
      int k4 = (li & 15) << 2;
      float4 v = make_float4(0.f, 0.f, 0.f, 0.f);
      int gr = rowbase + r;
      if (gr < NN) v = *(const float4*)(A + (size_t)gr * FF + kc + k4);
      sA[r * 65 + k4 + 0] = v.x;
      sA[r * 65 + k4 + 1] = v.y;
      sA[r * 65 + k4 + 2] = v.z;
      sA[r * 65 + k4 + 3] = v.w;
    }
#pragma unroll
    for (int i = 0; i < 8; ++i) {
      int li = tid + i * 256;
      int kk = li >> 5;
      int c4 = (li & 31) << 2;
      *(float4*)(sW + kk * 128 + c4) = *(const float4*)(W + (size_t)(kc + kk) * 128 + c4);
    }
    __syncthreads();
#pragma unroll 8
    for (int kk = 0; kk < 64; ++kk) {
      float av[4];
      av[0] = sA[(ty4 + 0) * 65 + kk];
      av[1] = sA[(ty4 + 1) * 65 + kk];
      av[2] = sA[(ty4 + 2) * 65 + kk];
      av[3] = sA[(ty4 + 3) * 65 + kk];
      float4 w0 = *(const float4*)(sW + kk * 128 + tx8);
      float4 w1 = *(const float4*)(sW + kk * 128 + tx8 + 4);
      float wv[8] = {w0.x, w0.y, w0.z, w0.w, w1.x, w1.y, w1.z, w1.w};
#pragma unroll
      for (int i = 0; i < 4; ++i)
#pragma unroll
        for (int j = 0; j < 8; ++j) acc[i][j] = fmaf(av[i], wv[j], acc[i][j]);
    }
    __syncthreads();
  }
#pragma unroll
  for (int i = 0; i < 4; ++i) {
    int gr = rowbase + ty4 + i;
    if (gr < NN) {
      uint4 o;
      o.x = packbf(acc[i][0], acc[i][1]);
      o.y = packbf(acc[i][2], acc[i][3]);
      o.z = packbf(acc[i][4], acc[i][5]);
      o.w = packbf(acc[i][6], acc[i][7]);
      *(uint4*)(Cb + (size_t)gr * 64 + tx * 4) = o;
    }
  }
}

// ---------- aggregation: A[n] = relu(sum_e w*B[src] + bias), BN partials ----------
// one wave per node; lane handles channels 2*lane,2*lane+1 (one packed bf16 uint).
// 32-edge chunks; lanes 0..31 stage (csrc,cw); 4 fully-unrolled groups of 8 with
// constant-lane shuffles (v_readlane) and uniform skip; 8 independent acc pairs.
__global__ __launch_bounds__(256) void k_agg(const unsigned* __restrict__ Bb,
                                             const int* __restrict__ rowptr,
                                             const int* __restrict__ csrc,
                                             const float* __restrict__ cw,
                                             const float* __restrict__ bias,
                                             float* __restrict__ Aout,
                                             float* __restrict__ bnbuf) {
  const int lane = threadIdx.x & 63;
  const int wave = threadIdx.x >> 6;
  const int c = lane * 2;
  const int gwave = blockIdx.x * 4 + wave;
  const int nwaves = gridDim.x * 4;
  const float2 bv = *(const float2*)(bias + c);
  float s0 = 0.f, s1 = 0.f, q0 = 0.f, q1 = 0.f;
  for (int n = gwave; n < NN; n += nwaves) {
    const int beg = rowptr[n];
    const int end = rowptr[n + 1];
    float ax[8], ay[8];
#pragma unroll
    for (int j = 0; j < 8; ++j) { ax[j] = 0.f; ay[j] = 0.f; }
    for (int base = beg; base < end; base += 32) {
      const int myj = base + lane;
      int msrc = 0;
      float mw = 0.f;
      if (lane < 32 && myj < end) {
        msrc = csrc[myj];
        mw = cw[myj];
      }
#pragma unroll
      for (int g = 0; g < 4; ++g) {
        if (base + g * 8 < end) {   // wave-uniform branch
          int is[8]; float wv[8]; unsigned us[8];
#pragma unroll
          for (int j = 0; j < 8; ++j) {
            is[j] = __shfl(msrc, g * 8 + j);
            wv[j] = __shfl(mw, g * 8 + j);
          }
#pragma unroll
          for (int j = 0; j < 8; ++j) us[j] = Bb[(size_t)is[j] * 64 + lane];
#pragma unroll
          for (int j = 0; j < 8; ++j) {
            ax[j] = fmaf(wv[j], bflo(us[j]), ax[j]);
            ay[j] = fmaf(wv[j], bfhi(us[j]), ay[j]);
          }
        }
      }
    }
    float rx = ((ax[0] + ax[1]) + (ax[2] + ax[3])) + ((ax[4] + ax[5]) + (ax[6] + ax[7]));
    float ry = ((ay[0] + ay[1]) + (ay[2] + ay[3])) + ((ay[4] + ay[5]) + (ay[6] + ay[7]));
    rx = fmaxf(rx + bv.x, 0.f);
    ry = fmaxf(ry + bv.y, 0.f);
    *(float2*)(Aout + (size_t)n * FF + c) = make_float2(rx, ry);
    s0 += rx; s1 += ry;
    q0 = fmaf(rx, rx, q0); q1 = fmaf(ry, ry, q1);
  }
  __shared__ float sred[4][256];
  sred[wave][c] = s0;
  sred[wave][c + 1] = s1;
  sred[wave][128 + c] = q0;
  sred[wave][128 + c + 1] = q1;
  __syncthreads();
  const int t = threadIdx.x;
  float tot = sred[0][t] + sred[1][t] + sred[2][t] + sred[3][t];
  atomicAdd(&bnbuf[t], tot);
}

__global__ __launch_bounds__(128) void k_bnfin(const float* __restrict__ bnbuf,
                                               const float* __restrict__ gamma,
                                               const float* __restrict__ beta,
                                               float* __restrict__ bnsc) {
  const int c = threadIdx.x;
  float mu = bnbuf[c] * (1.0f / NN);
  float var = bnbuf[128 + c] * (1.0f / NN) - mu * mu;
  float inv = rsqrtf(var + EPSF);
  float sc = gamma[c] * inv;
  bnsc[c] = sc;
  bnsc[128 + c] = beta[c] - mu * sc;
}

// BN apply in-place + pooled (graph-sorted, 8 blocks per graph, 1 atomic/channel/block)
__global__ __launch_bounds__(128) void k_bnapply(float* __restrict__ A,
                                                 const float* __restrict__ bnsc,
                                                 const int* __restrict__ gstart,
                                                 float* __restrict__ pooledt) {
  const int g = blockIdx.x >> 3;
  const int sub = blockIdx.x & 7;
  const int s = gstart[g];
  const int e = gstart[g + 1];
  const int cnt = e - s;
  if (cnt <= 0) return;
  const int per = (cnt + 7) >> 3;
  const int ns = s + sub * per;
  const int ne = min(ns + per, e);
  if (ns >= ne) return;
  const int c = threadIdx.x;
  const float sc = bnsc[c];
  const float sh = bnsc[128 + c];
  float acc = 0.f;
  for (int n = ns; n < ne; ++n) {
    float v = fmaf(A[(size_t)n * FF + c], sc, sh);
    A[(size_t)n * FF + c] = v;
    acc += v;
  }
  atomicAdd(&pooledt[(size_t)g * 512 + c], acc);
}

// ---------- head ----------

__global__ __launch_bounds__(128) void k_z1(const float* __restrict__ pooled,
                                            const float* __restrict__ W1,
                                            const float* __restrict__ b1,
                                            float* __restrict__ z1) {
  __shared__ float sp[512];
  const int g = blockIdx.x;
  for (int i = threadIdx.x; i < 512; i += 128) sp[i] = pooled[(size_t)g * 512 + i];
  __syncthreads();
  const int c = threadIdx.x;
  float acc = b1[c];
  for (int j = 0; j < 512; ++j) acc = fmaf(sp[j], W1[j * 128 + c], acc);
  z1[(size_t)g * 128 + c] = acc;
}

__global__ __launch_bounds__(128) void k_zstat(const float* __restrict__ z1,
                                               const float* __restrict__ g1,
                                               const float* __restrict__ bt1,
                                               float* __restrict__ zsc) {
  const int c = threadIdx.x;
  float s = 0.f, q = 0.f;
  for (int g = 0; g < GG; ++g) {
    float v = z1[g * 128 + c];
    s += v;
    q = fmaf(v, v, q);
  }
  float mu = s * (1.0f / GG);
  float var = q * (1.0f / GG) - mu * mu;
  float inv = rsqrtf(var + EPSF);
  float sc = g1[c] * inv;
  zsc[c] = sc;
  zsc[128 + c] = bt1[c] - mu * sc;
}

__global__ __launch_bounds__(128) void k_out(const float* __restrict__ z1,
                                             const float* __restrict__ zsc,
                                             const float* __restrict__ W2,
                                             const float* __restrict__ b2,
                                             float* __restrict__ out) {
  __shared__ float zr[128];
  const int g = blockIdx.x;
  const int c = threadIdx.x;
  zr[c] = fmaxf(fmaf(z1[(size_t)g * 128 + c], zsc[c], zsc[128 + c]), 0.f);
  __syncthreads();
  if (c < OUTC) {
    float acc = b2[c];
    for (int k = 0; k < 128; ++k) acc = fmaf(zr[k], W2[k * OUTC + c], acc);
    out[(size_t)g * OUTC + c] = acc;
  }
}

// ---------- launch ----------

extern "C" void kernel_launch(void* const* d_in, const int* in_sizes, int n_in,
                              void* d_out, int out_size, void* d_ws, size_t ws_size,
                              hipStream_t stream) {
  const float* x      = (const float*)d_in[0];
  const int*   ei     = (const int*)d_in[1];
  const int*   batch  = (const int*)d_in[2];
  const float* Ws     = (const float*)d_in[3];
  const float* bs     = (const float*)d_in[4];
  const float* gammas = (const float*)d_in[5];
  const float* betas  = (const float*)d_in[6];
  const float* W1     = (const float*)d_in[7];
  const float* b1     = (const float*)d_in[8];
  const float* g1     = (const float*)d_in[9];
  const float* bt1    = (const float*)d_in[10];
  const float* W2     = (const float*)d_in[11];
  const float* b2     = (const float*)d_in[12];
  float* out = (float*)d_out;

  char* ws = (char*)d_ws;
  size_t off = 0;
  auto alloc = [&](size_t bytes) -> void* {
    void* p = ws + off;
    off = (off + bytes + 255) & ~(size_t)255;
    return p;
  };
  // zero-initialized region (single memset)
  int*   deg    = (int*)alloc((size_t)NN * 4);
  int*   cnt    = (int*)alloc((size_t)NN * 4);
  float* bnbuf  = (float*)alloc((size_t)LL * 256 * 4);
  float* pooled = (float*)alloc((size_t)GG * 512 * 4);
  size_t zero_bytes = off;
  // rest
  float*    A      = (float*)alloc((size_t)NN * FF * 4);
  unsigned* Bb     = (unsigned*)alloc((size_t)NN * 64 * 4);   // packed bf16 H@W
  int*      csrc   = (int*)alloc((size_t)EE * 4);
  float*    cw     = (float*)alloc((size_t)EE * 4);
  float*    dinv   = (float*)alloc((size_t)NN * 4);
  int*      rowptr = (int*)alloc((size_t)(NN + 1) * 4);
  int*      bsum   = (int*)alloc((size_t)NSCB * 4);
  int*      gstart = (int*)alloc((size_t)(GG + 1) * 4);
  float*    z1     = (float*)alloc((size_t)GG * FF * 4);
  float*    bnsc   = (float*)alloc(256 * 4);
  float*    zsc    = (float*)alloc(256 * 4);
  (void)ws_size; (void)in_sizes; (void)n_in; (void)out_size;

  hipMemsetAsync(d_ws, 0, zero_bytes, stream);

  k_deg<<<(EE + 255) / 256, 256, 0, stream>>>(ei + EE, deg);
  k_dinv<<<(NN + 255) / 256, 256, 0, stream>>>(deg, dinv);
  k_bsum<<<NSCB, 256, 0, stream>>>(deg, bsum);
  k_rowptr<<<NSCB, 256, 0, stream>>>(deg, bsum, rowptr);
  k_fill<<<(EE + 255) / 256, 256, 0, stream>>>(ei, rowptr, cnt, dinv, csrc, cw);
  k_bounds<<<(NN + 255) / 256, 256, 0, stream>>>(batch, gstart);

  for (int t = 0; t < LL; ++t) {
    const float* hin = (t == 0) ? x : A;
    k_gemm<<<(NN + 63) / 64, 256, 0, stream>>>(hin, Ws + (size_t)t * FF * FF, Bb);
    k_agg<<<2048, 256, 0, stream>>>(Bb, rowptr, csrc, cw, bs + t * FF, A, bnbuf + t * 256);
    k_bnfin<<<1, 128, 0, stream>>>(bnbuf + t * 256, gammas + t * FF, betas + t * FF, bnsc);
    k_bnapply<<<GG * 8, 128, 0, stream>>>(A, bnsc, gstart, pooled + t * FF);
  }

  k_z1<<<GG, 128, 0, stream>>>(pooled, W1, b1, z1);
  k_zstat<<<1, 128, 0, stream>>>(z1, g1, bt1, zsc);
  k_out<<<GG, 128, 0, stream>>>(z1, zsc, W2, b2, out);
}

// Round 5
// 867.817 us; speedup vs baseline: 1.7292x; 1.1568x over previous
//
#include <hip/hip_runtime.h>

#define NN 100000
#define EE 1600000
#define FF 128
#define LL 4
#define GG 512
#define OUTC 10
#define EPSF 1e-5f
#define NSCB ((NN + 255) / 256)   // 391 scan blocks

typedef __attribute__((ext_vector_type(8))) short short8;
typedef __attribute__((ext_vector_type(4))) float f32x4;

__device__ inline unsigned bf16rne(float f) {
  unsigned u = __float_as_uint(f);
  return (u + 0x7fffu + ((u >> 16) & 1u)) >> 16;
}
__device__ inline unsigned packbf(float lo, float hi) {
  return bf16rne(lo) | (bf16rne(hi) << 16);
}
__device__ inline float bflo(unsigned u) { return __uint_as_float(u << 16); }
__device__ inline float bfhi(unsigned u) { return __uint_as_float(u & 0xffff0000u); }

// ---------- graph setup ----------

__global__ __launch_bounds__(256) void k_deg(const int* __restrict__ col, int* __restrict__ deg) {
  int e = blockIdx.x * 256 + threadIdx.x;
  if (e < EE) atomicAdd(&deg[col[e]], 1);
}

__global__ __launch_bounds__(256) void k_dinv(const int* __restrict__ deg, float* __restrict__ dinv) {
  int n = blockIdx.x * 256 + threadIdx.x;
  if (n < NN) {
    int d = deg[n];
    dinv[n] = d > 0 ? rsqrtf((float)d) : 0.0f;
  }
}

// per-block degree sums (391 blocks x 256)
__global__ __launch_bounds__(256) void k_bsum(const int* __restrict__ deg, int* __restrict__ bsum) {
  int i = blockIdx.x * 256 + threadIdx.x;
  int v = (i < NN) ? deg[i] : 0;
#pragma unroll
  for (int off = 32; off > 0; off >>= 1) v += __shfl_down(v, off, 64);
  __shared__ int ws[4];
  if ((threadIdx.x & 63) == 0) ws[threadIdx.x >> 6] = v;
  __syncthreads();
  if (threadIdx.x == 0) bsum[blockIdx.x] = ws[0] + ws[1] + ws[2] + ws[3];
}

// each block: scan all block sums in LDS (redundant), local scan of its 256 degs,
// write exclusive rowptr. rowptr[NN] = EE (constant).
__global__ __launch_bounds__(256) void k_rowptr(const int* __restrict__ deg,
                                                const int* __restrict__ bsum,
                                                int* __restrict__ rowptr) {
  __shared__ int sb[512];
  __shared__ int sd[256];
  const int t = threadIdx.x;
  sb[t]       = (t < NSCB) ? bsum[t] : 0;
  sb[t + 256] = (t + 256 < NSCB) ? bsum[t + 256] : 0;
  __syncthreads();
#pragma unroll
  for (int off = 1; off < 512; off <<= 1) {
    int v0 = (t >= off) ? sb[t - off] : 0;
    int v1 = sb[t + 256 - off];
    __syncthreads();
    sb[t] += v0;
    sb[t + 256] += v1;
    __syncthreads();
  }
  const int bpre = (blockIdx.x == 0) ? 0 : sb[blockIdx.x - 1];
  const int i = blockIdx.x * 256 + t;
  const int d = (i < NN) ? deg[i] : 0;
  sd[t] = d;
  __syncthreads();
#pragma unroll
  for (int off = 1; off < 256; off <<= 1) {
    int v = (t >= off) ? sd[t - off] : 0;
    __syncthreads();
    sd[t] += v;
    __syncthreads();
  }
  if (i < NN) rowptr[i] = bpre + sd[t] - d;
  if (blockIdx.x == 0 && t == 0) rowptr[NN] = EE;
}

// build CSR: one interleaved (src, weight) int2 store per edge
__global__ __launch_bounds__(256) void k_fill(const int* __restrict__ ei,
                                              const int* __restrict__ rowptr,
                                              int* __restrict__ cnt,
                                              const float* __restrict__ dinv,
                                              int2* __restrict__ ecw) {
  int e = blockIdx.x * 256 + threadIdx.x;
  if (e >= EE) return;
  int r = ei[e];
  int cl = ei[EE + e];
  int slot = rowptr[cl] + atomicAdd(&cnt[cl], 1);
  ecw[slot] = make_int2(r, __float_as_int(dinv[r] * dinv[cl]));
}

// batch is sorted: gstart[g] = first node of graph g; gstart[GG] = NN
__global__ __launch_bounds__(256) void k_bounds(const int* __restrict__ batch, int* __restrict__ gstart) {
  int n = blockIdx.x * 256 + threadIdx.x;
  if (n >= NN) return;
  int b = batch[n];
  if (n == 0) {
    for (int g = 0; g <= b; ++g) gstart[g] = 0;
  } else {
    int bp = batch[n - 1];
    for (int g = bp + 1; g <= b; ++g) gstart[g] = n;
  }
  if (n == NN - 1) {
    for (int g = b + 1; g <= GG; ++g) gstart[g] = NN;
  }
}

// ---------- bf16 conversions ----------

// x[N,128] fp32 -> Ab packed bf16 pairs
__global__ __launch_bounds__(256) void k_cvt(const float* __restrict__ x, unsigned* __restrict__ Ab) {
  int i = blockIdx.x * 256 + threadIdx.x;
  if (i < NN * 64) {
    float2 v = *(const float2*)(x + (size_t)i * 2);
    Ab[i] = packbf(v.x, v.y);
  }
}

// W[L,128,128] fp32 -> per-layer MFMA B-fragments, hi/lo bf16 split.
// frag index: ((t*4 + kc)*8 + ct)*2 + which, 64 lanes * 16B each.
__global__ __launch_bounds__(256) void k_wcvt(const float* __restrict__ Ws, uint4* __restrict__ Wf) {
  int tid = blockIdx.x * 256 + threadIdx.x;   // 0..16383
  int t = tid >> 12;
  int r = tid & 4095;
  int lane = r & 63;
  int which = (r >> 6) & 1;
  int ct = (r >> 7) & 7;
  int kc = r >> 10;
  int n = ct * 16 + (lane & 15);
  int k0 = kc * 32 + (lane >> 4) * 8;
  const float* W = Ws + t * 16384;
  unsigned h[8];
#pragma unroll
  for (int j = 0; j < 8; ++j) {
    float w = W[(k0 + j) * 128 + n];
    unsigned hb = bf16rne(w);
    if (which == 0) {
      h[j] = hb;
    } else {
      float hf = __uint_as_float(hb << 16);
      h[j] = bf16rne(w - hf);
    }
  }
  uint4 o;
  o.x = h[0] | (h[1] << 16);
  o.y = h[2] | (h[3] << 16);
  o.z = h[4] | (h[5] << 16);
  o.w = h[6] | (h[7] << 16);
  Wf[tid] = o;
}

// ---------- per-layer GEMM via MFMA: Bb[N,128](packed bf16) = Ab @ (Whi+Wlo) ----------
// block 256 = 4 waves; wave w: rows blk*64+16w..+15, all 128 cols (8 col-tiles).
// fp32 accumulate; epilogue packs channel pairs via shfl_xor into gather layout.
__global__ __launch_bounds__(256) void k_mm(const unsigned* __restrict__ Ab,
                                            const uint4* __restrict__ Wf,
                                            unsigned* __restrict__ Bb) {
  const int lane = threadIdx.x & 63;
  const int w = threadIdx.x >> 6;
  const int quad = lane >> 4;
  const int m = lane & 15;
  const int rowbase = blockIdx.x * 64 + w * 16;
  const int arow = min(rowbase + m, NN - 1);
  const uint4* A4 = (const uint4*)Ab;
  f32x4 acc[8];
#pragma unroll
  for (int ct = 0; ct < 8; ++ct) acc[ct] = (f32x4){0.f, 0.f, 0.f, 0.f};
#pragma unroll
  for (int kc = 0; kc < 4; ++kc) {
    uint4 av = A4[arow * 16 + kc * 4 + quad];
    short8 af = *(short8*)&av;
#pragma unroll
    for (int ct = 0; ct < 8; ++ct) {
      uint4 bh = Wf[((kc * 8 + ct) * 2 + 0) * 64 + lane];
      uint4 bl = Wf[((kc * 8 + ct) * 2 + 1) * 64 + lane];
      acc[ct] = __builtin_amdgcn_mfma_f32_16x16x32_bf16(af, *(short8*)&bh, acc[ct], 0, 0, 0);
      acc[ct] = __builtin_amdgcn_mfma_f32_16x16x32_bf16(af, *(short8*)&bl, acc[ct], 0, 0, 0);
    }
  }
#pragma unroll
  for (int ct = 0; ct < 8; ++ct) {
#pragma unroll
    for (int r = 0; r < 4; ++r) {
      float v = acc[ct][r];
      float vo = __shfl_xor(v, 1);
      int row = rowbase + quad * 4 + r;
      if ((lane & 1) == 0 && row < NN) {
        Bb[row * 64 + ct * 8 + (m >> 1)] = packbf(v, vo);
      }
    }
  }
}

// ---------- aggregation: A[n] = relu(sum_e w*B[src] + bias), BN partials ----------
__global__ __launch_bounds__(256) void k_agg(const unsigned* __restrict__ Bb,
                                             const int* __restrict__ rowptr,
                                             const int2* __restrict__ ecw,
                                             const float* __restrict__ bias,
                                             float* __restrict__ Aout,
                                             float* __restrict__ bnbuf) {
  const int lane = threadIdx.x & 63;
  const int wave = threadIdx.x >> 6;
  const int c = lane * 2;
  const int gwave = blockIdx.x * 4 + wave;
  const int nwaves = gridDim.x * 4;
  const float2 bv = *(const float2*)(bias + c);
  float s0 = 0.f, s1 = 0.f, q0 = 0.f, q1 = 0.f;
  for (int n = gwave; n < NN; n += nwaves) {
    const int beg = rowptr[n];
    const int end = rowptr[n + 1];
    float ax[8], ay[8];
#pragma unroll
    for (int j = 0; j < 8; ++j) { ax[j] = 0.f; ay[j] = 0.f; }
    for (int base = beg; base < end; base += 32) {
      const int myj = base + lane;
      int msrc = 0;
      float mw = 0.f;
      if (lane < 32 && myj < end) {
        int2 p = ecw[myj];
        msrc = p.x;
        mw = __int_as_float(p.y);
      }
#pragma unroll
      for (int g = 0; g < 4; ++g) {
        if (base + g * 8 < end) {   // wave-uniform branch
          int is[8]; float wv[8]; unsigned us[8];
#pragma unroll
          for (int j = 0; j < 8; ++j) {
            is[j] = __shfl(msrc, g * 8 + j);
            wv[j] = __shfl(mw, g * 8 + j);
          }
#pragma unroll
          for (int j = 0; j < 8; ++j) us[j] = Bb[((unsigned)is[j] << 6) + (unsigned)lane];
#pragma unroll
          for (int j = 0; j < 8; ++j) {
            ax[j] = fmaf(wv[j], bflo(us[j]), ax[j]);
            ay[j] = fmaf(wv[j], bfhi(us[j]), ay[j]);
          }
        }
      }
    }
    float rx = ((ax[0] + ax[1]) + (ax[2] + ax[3])) + ((ax[4] + ax[5]) + (ax[6] + ax[7]));
    float ry = ((ay[0] + ay[1]) + (ay[2] + ay[3])) + ((ay[4] + ay[5]) + (ay[6] + ay[7]));
    rx = fmaxf(rx + bv.x, 0.f);
    ry = fmaxf(ry + bv.y, 0.f);
    *(float2*)(Aout + (size_t)n * FF + c) = make_float2(rx, ry);
    s0 += rx; s1 += ry;
    q0 = fmaf(rx, rx, q0); q1 = fmaf(ry, ry, q1);
  }
  __shared__ float sred[4][256];
  sred[wave][c] = s0;
  sred[wave][c + 1] = s1;
  sred[wave][128 + c] = q0;
  sred[wave][128 + c + 1] = q1;
  __syncthreads();
  const int t = threadIdx.x;
  float tot = sred[0][t] + sred[1][t] + sred[2][t] + sred[3][t];
  atomicAdd(&bnbuf[t], tot);
}

__global__ __launch_bounds__(128) void k_bnfin(const float* __restrict__ bnbuf,
                                               const float* __restrict__ gamma,
                                               const float* __restrict__ beta,
                                               float* __restrict__ bnsc) {
  const int c = threadIdx.x;
  float mu = bnbuf[c] * (1.0f / NN);
  float var = bnbuf[128 + c] * (1.0f / NN) - mu * mu;
  float inv = rsqrtf(var + EPSF);
  float sc = gamma[c] * inv;
  bnsc[c] = sc;
  bnsc[128 + c] = beta[c] - mu * sc;
}

// BN apply + pool + emit packed bf16 for next layer's MFMA GEMM.
// thread t: channel pair (2*(t&63), +1), node offset t>>6 (2 nodes/iter).
__global__ __launch_bounds__(128) void k_bnapply(const float* __restrict__ A,
                                                 const float* __restrict__ bnsc,
                                                 const int* __restrict__ gstart,
                                                 float* __restrict__ pooledt,
                                                 unsigned* __restrict__ Ab) {
  const int g = blockIdx.x >> 3;
  const int sub = blockIdx.x & 7;
  const int s = gstart[g];
  const int e = gstart[g + 1];
  const int cnt = e - s;
  if (cnt <= 0) return;
  const int per = (cnt + 7) >> 3;
  const int ns = s + sub * per;
  const int ne = min(ns + per, e);
  if (ns >= ne) return;
  const int cp = threadIdx.x & 63;
  const int half = threadIdx.x >> 6;
  const float2 sc = *(const float2*)(bnsc + 2 * cp);
  const float2 sh = *(const float2*)(bnsc + 128 + 2 * cp);
  float accx = 0.f, accy = 0.f;
  for (int n = ns + half; n < ne; n += 2) {
    float2 v = *(const float2*)(A + (size_t)n * FF + 2 * cp);
    float vx = fmaf(v.x, sc.x, sh.x);
    float vy = fmaf(v.y, sc.y, sh.y);
    Ab[n * 64 + cp] = packbf(vx, vy);
    accx += vx;
    accy += vy;
  }
  atomicAdd(&pooledt[(size_t)g * 512 + 2 * cp], accx);
  atomicAdd(&pooledt[(size_t)g * 512 + 2 * cp + 1], accy);
}

// ---------- head ----------

__global__ __launch_bounds__(128) void k_z1(const float* __restrict__ pooled,
                                            const float* __restrict__ W1,
                                            const float* __restrict__ b1,
                                            float* __restrict__ z1) {
  __shared__ float sp[512];
  const int g = blockIdx.x;
  for (int i = threadIdx.x; i < 512; i += 128) sp[i] = pooled[(size_t)g * 512 + i];
  __syncthreads();
  const int c = threadIdx.x;
  float acc = b1[c];
  for (int j = 0; j < 512; ++j) acc = fmaf(sp[j], W1[j * 128 + c], acc);
  z1[(size_t)g * 128 + c] = acc;
}

__global__ __launch_bounds__(128) void k_zstat(const float* __restrict__ z1,
                                               const float* __restrict__ g1,
                                               const float* __restrict__ bt1,
                                               float* __restrict__ zsc) {
  const int c = threadIdx.x;
  float s = 0.f, q = 0.f;
  for (int g = 0; g < GG; ++g) {
    float v = z1[g * 128 + c];
    s += v;
    q = fmaf(v, v, q);
  }
  float mu = s * (1.0f / GG);
  float var = q * (1.0f / GG) - mu * mu;
  float inv = rsqrtf(var + EPSF);
  float sc = g1[c] * inv;
  zsc[c] = sc;
  zsc[128 + c] = bt1[c] - mu * sc;
}

__global__ __launch_bounds__(128) void k_out(const float* __restrict__ z1,
                                             const float* __restrict__ zsc,
                                             const float* __restrict__ W2,
                                             const float* __restrict__ b2,
                                             float* __restrict__ out) {
  __shared__ float zr[128];
  const int g = blockIdx.x;
  const int c = threadIdx.x;
  zr[c] = fmaxf(fmaf(z1[(size_t)g * 128 + c], zsc[c], zsc[128 + c]), 0.f);
  __syncthreads();
  if (c < OUTC) {
    float acc = b2[c];
    for (int k = 0; k < 128; ++k) acc = fmaf(zr[k], W2[k * OUTC + c], acc);
    out[(size_t)g * OUTC + c] = acc;
  }
}

// ---------- launch ----------

extern "C" void kernel_launch(void* const* d_in, const int* in_sizes, int n_in,
                              void* d_out, int out_size, void* d_ws, size_t ws_size,
                              hipStream_t stream) {
  const float* x      = (const float*)d_in[0];
  const int*   ei     = (const int*)d_in[1];
  const int*   batch  = (const int*)d_in[2];
  const float* Ws     = (const float*)d_in[3];
  const float* bs     = (const float*)d_in[4];
  const float* gammas = (const float*)d_in[5];
  const float* betas  = (const float*)d_in[6];
  const float* W1     = (const float*)d_in[7];
  const float* b1     = (const float*)d_in[8];
  const float* g1     = (const float*)d_in[9];
  const float* bt1    = (const float*)d_in[10];
  const float* W2     = (const float*)d_in[11];
  const float* b2     = (const float*)d_in[12];
  float* out = (float*)d_out;

  char* ws = (char*)d_ws;
  size_t off = 0;
  auto alloc = [&](size_t bytes) -> void* {
    void* p = ws + off;
    off = (off + bytes + 255) & ~(size_t)255;
    return p;
  };
  // zero-initialized region (single memset)
  int*   deg    = (int*)alloc((size_t)NN * 4);
  int*   cnt    = (int*)alloc((size_t)NN * 4);
  float* bnbuf  = (float*)alloc((size_t)LL * 256 * 4);
  float* pooled = (float*)alloc((size_t)GG * 512 * 4);
  size_t zero_bytes = off;
  // rest
  float*    A      = (float*)alloc((size_t)NN * FF * 4);   // fp32 BN input
  unsigned* Ab     = (unsigned*)alloc((size_t)NN * 64 * 4); // packed bf16 GEMM input
  unsigned* Bb     = (unsigned*)alloc((size_t)NN * 64 * 4); // packed bf16 H@W (gather src)
  int2*     ecw    = (int2*)alloc((size_t)EE * 8);
  float*    dinv   = (float*)alloc((size_t)NN * 4);
  int*      rowptr = (int*)alloc((size_t)(NN + 1) * 4);
  int*      bsum   = (int*)alloc((size_t)NSCB * 4);
  int*      gstart = (int*)alloc((size_t)(GG + 1) * 4);
  uint4*    Wf     = (uint4*)alloc((size_t)LL * 4096 * 16); // MFMA W fragments (hi/lo)
  float*    z1     = (float*)alloc((size_t)GG * FF * 4);
  float*    bnsc   = (float*)alloc(256 * 4);
  float*    zsc    = (float*)alloc(256 * 4);
  (void)ws_size; (void)in_sizes; (void)n_in; (void)out_size;

  hipMemsetAsync(d_ws, 0, zero_bytes, stream);

  k_deg<<<(EE + 255) / 256, 256, 0, stream>>>(ei + EE, deg);
  k_dinv<<<(NN + 255) / 256, 256, 0, stream>>>(deg, dinv);
  k_bsum<<<NSCB, 256, 0, stream>>>(deg, bsum);
  k_rowptr<<<NSCB, 256, 0, stream>>>(deg, bsum, rowptr);
  k_fill<<<(EE + 255) / 256, 256, 0, stream>>>(ei, rowptr, cnt, dinv, ecw);
  k_bounds<<<(NN + 255) / 256, 256, 0, stream>>>(batch, gstart);
  k_cvt<<<(NN * 64 + 255) / 256, 256, 0, stream>>>(x, Ab);
  k_wcvt<<<64, 256, 0, stream>>>(Ws, Wf);

  for (int t = 0; t < LL; ++t) {
    k_mm<<<(NN + 63) / 64, 256, 0, stream>>>(Ab, Wf + (size_t)t * 4096, Bb);
    k_agg<<<2048, 256, 0, stream>>>(Bb, rowptr, ecw, bs + t * FF, A, bnbuf + t * 256);
    k_bnfin<<<1, 128, 0, stream>>>(bnbuf + t * 256, gammas + t * FF, betas + t * FF, bnsc);
    k_bnapply<<<GG * 8, 128, 0, stream>>>(A, bnsc, gstart, pooled + t * FF, Ab);
  }

  k_z1<<<GG, 128, 0, stream>>>(pooled, W1, b1, z1);
  k_zstat<<<1, 128, 0, stream>>>(z1, g1, bt1, zsc);
  k_out<<<GG, 128, 0, stream>>>(z1, zsc, W2, b2, out);
}

// Round 6
// 858.208 us; speedup vs baseline: 1.7486x; 1.0112x over previous
//
#include <hip/hip_runtime.h>

#define NN 100000
#define EE 1600000
#define FF 128
#define LL 4
#define GG 512
#define OUTC 10
#define EPSF 1e-5f
#define NSCB ((NN + 255) / 256)   // 391 scan blocks

typedef __attribute__((ext_vector_type(8))) short short8;
typedef __attribute__((ext_vector_type(4))) float f32x4;

__device__ inline unsigned bf16rne(float f) {
  unsigned u = __float_as_uint(f);
  return (u + 0x7fffu + ((u >> 16) & 1u)) >> 16;
}
__device__ inline unsigned packbf(float lo, float hi) {
  return bf16rne(lo) | (bf16rne(hi) << 16);
}
__device__ inline float bflo(unsigned u) { return __uint_as_float(u << 16); }
__device__ inline float bfhi(unsigned u) { return __uint_as_float(u & 0xffff0000u); }

// ---------- graph setup ----------

__global__ __launch_bounds__(256) void k_deg(const int* __restrict__ col, int* __restrict__ deg) {
  int e = blockIdx.x * 256 + threadIdx.x;
  if (e < EE) atomicAdd(&deg[col[e]], 1);
}

__global__ __launch_bounds__(256) void k_dinv(const int* __restrict__ deg, float* __restrict__ dinv) {
  int n = blockIdx.x * 256 + threadIdx.x;
  if (n < NN) {
    int d = deg[n];
    dinv[n] = d > 0 ? rsqrtf((float)d) : 0.0f;
  }
}

// per-block degree sums (391 blocks x 256)
__global__ __launch_bounds__(256) void k_bsum(const int* __restrict__ deg, int* __restrict__ bsum) {
  int i = blockIdx.x * 256 + threadIdx.x;
  int v = (i < NN) ? deg[i] : 0;
#pragma unroll
  for (int off = 32; off > 0; off >>= 1) v += __shfl_down(v, off, 64);
  __shared__ int ws[4];
  if ((threadIdx.x & 63) == 0) ws[threadIdx.x >> 6] = v;
  __syncthreads();
  if (threadIdx.x == 0) bsum[blockIdx.x] = ws[0] + ws[1] + ws[2] + ws[3];
}

// each block: scan all block sums in LDS (redundant), local scan of its 256 degs,
// write exclusive rowptr. rowptr[NN] = EE (constant).
__global__ __launch_bounds__(256) void k_rowptr(const int* __restrict__ deg,
                                                const int* __restrict__ bsum,
                                                int* __restrict__ rowptr) {
  __shared__ int sb[512];
  __shared__ int sd[256];
  const int t = threadIdx.x;
  sb[t]       = (t < NSCB) ? bsum[t] : 0;
  sb[t + 256] = (t + 256 < NSCB) ? bsum[t + 256] : 0;
  __syncthreads();
#pragma unroll
  for (int off = 1; off < 512; off <<= 1) {
    int v0 = (t >= off) ? sb[t - off] : 0;
    int v1 = sb[t + 256 - off];
    __syncthreads();
    sb[t] += v0;
    sb[t + 256] += v1;
    __syncthreads();
  }
  const int bpre = (blockIdx.x == 0) ? 0 : sb[blockIdx.x - 1];
  const int i = blockIdx.x * 256 + t;
  const int d = (i < NN) ? deg[i] : 0;
  sd[t] = d;
  __syncthreads();
#pragma unroll
  for (int off = 1; off < 256; off <<= 1) {
    int v = (t >= off) ? sd[t - off] : 0;
    __syncthreads();
    sd[t] += v;
    __syncthreads();
  }
  if (i < NN) rowptr[i] = bpre + sd[t] - d;
  if (blockIdx.x == 0 && t == 0) rowptr[NN] = EE;
}

// build CSR: one interleaved (src, weight) int2 store per edge
__global__ __launch_bounds__(256) void k_fill(const int* __restrict__ ei,
                                              const int* __restrict__ rowptr,
                                              int* __restrict__ cnt,
                                              const float* __restrict__ dinv,
                                              int2* __restrict__ ecw) {
  int e = blockIdx.x * 256 + threadIdx.x;
  if (e >= EE) return;
  int r = ei[e];
  int cl = ei[EE + e];
  int slot = rowptr[cl] + atomicAdd(&cnt[cl], 1);
  ecw[slot] = make_int2(r, __float_as_int(dinv[r] * dinv[cl]));
}

// batch is sorted: gstart[g] = first node of graph g; gstart[GG] = NN
__global__ __launch_bounds__(256) void k_bounds(const int* __restrict__ batch, int* __restrict__ gstart) {
  int n = blockIdx.x * 256 + threadIdx.x;
  if (n >= NN) return;
  int b = batch[n];
  if (n == 0) {
    for (int g = 0; g <= b; ++g) gstart[g] = 0;
  } else {
    int bp = batch[n - 1];
    for (int g = bp + 1; g <= b; ++g) gstart[g] = n;
  }
  if (n == NN - 1) {
    for (int g = b + 1; g <= GG; ++g) gstart[g] = NN;
  }
}

// ---------- bf16 conversions ----------

// x[N,128] fp32 -> Ab packed bf16 pairs
__global__ __launch_bounds__(256) void k_cvt(const float* __restrict__ x, unsigned* __restrict__ Ab) {
  int i = blockIdx.x * 256 + threadIdx.x;
  if (i < NN * 64) {
    float2 v = *(const float2*)(x + (size_t)i * 2);
    Ab[i] = packbf(v.x, v.y);
  }
}

// W[L,128,128] fp32 -> per-layer MFMA B-fragments, hi/lo bf16 split.
// frag index: ((t*4 + kc)*8 + ct)*2 + which, 64 lanes * 16B each.
__global__ __launch_bounds__(256) void k_wcvt(const float* __restrict__ Ws, uint4* __restrict__ Wf) {
  int tid = blockIdx.x * 256 + threadIdx.x;   // 0..16383
  int t = tid >> 12;
  int r = tid & 4095;
  int lane = r & 63;
  int which = (r >> 6) & 1;
  int ct = (r >> 7) & 7;
  int kc = r >> 10;
  int n = ct * 16 + (lane & 15);
  int k0 = kc * 32 + (lane >> 4) * 8;
  const float* W = Ws + t * 16384;
  unsigned h[8];
#pragma unroll
  for (int j = 0; j < 8; ++j) {
    float w = W[(k0 + j) * 128 + n];
    unsigned hb = bf16rne(w);
    if (which == 0) {
      h[j] = hb;
    } else {
      float hf = __uint_as_float(hb << 16);
      h[j] = bf16rne(w - hf);
    }
  }
  uint4 o;
  o.x = h[0] | (h[1] << 16);
  o.y = h[2] | (h[3] << 16);
  o.z = h[4] | (h[5] << 16);
  o.w = h[6] | (h[7] << 16);
  Wf[tid] = o;
}

// ---------- per-layer GEMM via MFMA: Bb[N,128](packed bf16) = Ab @ (Whi+Wlo) ----------
__global__ __launch_bounds__(256) void k_mm(const unsigned* __restrict__ Ab,
                                            const uint4* __restrict__ Wf,
                                            unsigned* __restrict__ Bb) {
  const int lane = threadIdx.x & 63;
  const int w = threadIdx.x >> 6;
  const int quad = lane >> 4;
  const int m = lane & 15;
  const int rowbase = blockIdx.x * 64 + w * 16;
  const int arow = min(rowbase + m, NN - 1);
  const uint4* A4 = (const uint4*)Ab;
  f32x4 acc[8];
#pragma unroll
  for (int ct = 0; ct < 8; ++ct) acc[ct] = (f32x4){0.f, 0.f, 0.f, 0.f};
#pragma unroll
  for (int kc = 0; kc < 4; ++kc) {
    uint4 av = A4[arow * 16 + kc * 4 + quad];
    short8 af = *(short8*)&av;
#pragma unroll
    for (int ct = 0; ct < 8; ++ct) {
      uint4 bh = Wf[((kc * 8 + ct) * 2 + 0) * 64 + lane];
      uint4 bl = Wf[((kc * 8 + ct) * 2 + 1) * 64 + lane];
      acc[ct] = __builtin_amdgcn_mfma_f32_16x16x32_bf16(af, *(short8*)&bh, acc[ct], 0, 0, 0);
      acc[ct] = __builtin_amdgcn_mfma_f32_16x16x32_bf16(af, *(short8*)&bl, acc[ct], 0, 0, 0);
    }
  }
#pragma unroll
  for (int ct = 0; ct < 8; ++ct) {
#pragma unroll
    for (int r = 0; r < 4; ++r) {
      float v = acc[ct][r];
      float vo = __shfl_xor(v, 1);
      int row = rowbase + quad * 4 + r;
      if ((lane & 1) == 0 && row < NN) {
        Bb[row * 64 + ct * 8 + (m >> 1)] = packbf(v, vo);
      }
    }
  }
}

// ---------- aggregation: Ar[n] = packbf(relu(sum_e w*B[src] + bias)), BN partials ----------
// one wave per node; lane = channel pair. 64-edge staged chunks (coalesced int2),
// prefetch next chunk's staging before processing current; groups of 16 with
// constant-lane shuffles -> 16 gathers in flight; 8 acc pairs.
__global__ __launch_bounds__(256) void k_agg(const unsigned* __restrict__ Bb,
                                             const int* __restrict__ rowptr,
                                             const int2* __restrict__ ecw,
                                             const float* __restrict__ bias,
                                             unsigned* __restrict__ Ar,
                                             float* __restrict__ bnbuf) {
  const int lane = threadIdx.x & 63;
  const int wave = threadIdx.x >> 6;
  const int c = lane * 2;
  const int gwave = blockIdx.x * 4 + wave;
  const int nwaves = gridDim.x * 4;
  const float2 bv = *(const float2*)(bias + c);
  float s0 = 0.f, s1 = 0.f, q0 = 0.f, q1 = 0.f;
  for (int n = gwave; n < NN; n += nwaves) {
    const int beg = rowptr[n];
    const int end = rowptr[n + 1];
    float ax[8], ay[8];
#pragma unroll
    for (int j = 0; j < 8; ++j) { ax[j] = 0.f; ay[j] = 0.f; }
    int2 stage = (beg + lane < end) ? ecw[beg + lane] : make_int2(0, 0);
    for (int base = beg; base < end; base += 64) {
      const int2 cur = stage;
      const int nb = base + 64;
      if (nb < end) {   // prefetch next chunk's staging (off critical path)
        const int j = nb + lane;
        stage = (j < end) ? ecw[j] : make_int2(0, 0);
      }
#pragma unroll
      for (int g = 0; g < 4; ++g) {
        if (base + g * 16 < end) {   // wave-uniform branch
          int is[16]; float wv[16]; unsigned us[16];
#pragma unroll
          for (int j = 0; j < 16; ++j) {
            is[j] = __shfl(cur.x, g * 16 + j);
            wv[j] = __shfl(__int_as_float(cur.y), g * 16 + j);
          }
#pragma unroll
          for (int j = 0; j < 16; ++j) us[j] = Bb[((unsigned)is[j] << 6) + (unsigned)lane];
#pragma unroll
          for (int j = 0; j < 16; ++j) {
            ax[j & 7] = fmaf(wv[j], bflo(us[j]), ax[j & 7]);
            ay[j & 7] = fmaf(wv[j], bfhi(us[j]), ay[j & 7]);
          }
        }
      }
    }
    float rx = ((ax[0] + ax[1]) + (ax[2] + ax[3])) + ((ax[4] + ax[5]) + (ax[6] + ax[7]));
    float ry = ((ay[0] + ay[1]) + (ay[2] + ay[3])) + ((ay[4] + ay[5]) + (ay[6] + ay[7]));
    rx = fmaxf(rx + bv.x, 0.f);
    ry = fmaxf(ry + bv.y, 0.f);
    Ar[(size_t)n * 64 + lane] = packbf(rx, ry);
    s0 += rx; s1 += ry;
    q0 = fmaf(rx, rx, q0); q1 = fmaf(ry, ry, q1);
  }
  __shared__ float sred[4][256];
  sred[wave][c] = s0;
  sred[wave][c + 1] = s1;
  sred[wave][128 + c] = q0;
  sred[wave][128 + c + 1] = q1;
  __syncthreads();
  const int t = threadIdx.x;
  float tot = sred[0][t] + sred[1][t] + sred[2][t] + sred[3][t];
  atomicAdd(&bnbuf[t], tot);
}

__global__ __launch_bounds__(128) void k_bnfin(const float* __restrict__ bnbuf,
                                               const float* __restrict__ gamma,
                                               const float* __restrict__ beta,
                                               float* __restrict__ bnsc) {
  const int c = threadIdx.x;
  float mu = bnbuf[c] * (1.0f / NN);
  float var = bnbuf[128 + c] * (1.0f / NN) - mu * mu;
  float inv = rsqrtf(var + EPSF);
  float sc = gamma[c] * inv;
  bnsc[c] = sc;
  bnsc[128 + c] = beta[c] - mu * sc;
}

// BN apply on packed-bf16 relu output + pool + emit packed bf16 next-layer GEMM input.
__global__ __launch_bounds__(128) void k_bnapply(const unsigned* __restrict__ Ar,
                                                 const float* __restrict__ bnsc,
                                                 const int* __restrict__ gstart,
                                                 float* __restrict__ pooledt,
                                                 unsigned* __restrict__ Ab) {
  const int g = blockIdx.x >> 3;
  const int sub = blockIdx.x & 7;
  const int s = gstart[g];
  const int e = gstart[g + 1];
  const int cnt = e - s;
  if (cnt <= 0) return;
  const int per = (cnt + 7) >> 3;
  const int ns = s + sub * per;
  const int ne = min(ns + per, e);
  if (ns >= ne) return;
  const int cp = threadIdx.x & 63;
  const int half = threadIdx.x >> 6;
  const float2 sc = *(const float2*)(bnsc + 2 * cp);
  const float2 sh = *(const float2*)(bnsc + 128 + 2 * cp);
  float accx = 0.f, accy = 0.f;
  for (int n = ns + half; n < ne; n += 2) {
    unsigned u = Ar[(size_t)n * 64 + cp];
    float vx = fmaf(bflo(u), sc.x, sh.x);
    float vy = fmaf(bfhi(u), sc.y, sh.y);
    Ab[(size_t)n * 64 + cp] = packbf(vx, vy);
    accx += vx;
    accy += vy;
  }
  atomicAdd(&pooledt[(size_t)g * 512 + 2 * cp], accx);
  atomicAdd(&pooledt[(size_t)g * 512 + 2 * cp + 1], accy);
}

// ---------- head ----------

__global__ __launch_bounds__(128) void k_z1(const float* __restrict__ pooled,
                                            const float* __restrict__ W1,
                                            const float* __restrict__ b1,
                                            float* __restrict__ z1) {
  __shared__ float sp[512];
  const int g = blockIdx.x;
  for (int i = threadIdx.x; i < 512; i += 128) sp[i] = pooled[(size_t)g * 512 + i];
  __syncthreads();
  const int c = threadIdx.x;
  float acc = b1[c];
  for (int j = 0; j < 512; ++j) acc = fmaf(sp[j], W1[j * 128 + c], acc);
  z1[(size_t)g * 128 + c] = acc;
}

__global__ __launch_bounds__(128) void k_zstat(const float* __restrict__ z1,
                                               const float* __restrict__ g1,
                                               const float* __restrict__ bt1,
                                               float* __restrict__ zsc) {
  const int c = threadIdx.x;
  float s = 0.f, q = 0.f;
  for (int g = 0; g < GG; ++g) {
    float v = z1[g * 128 + c];
    s += v;
    q = fmaf(v, v, q);
  }
  float mu = s * (1.0f / GG);
  float var = q * (1.0f / GG) - mu * mu;
  float inv = rsqrtf(var + EPSF);
  float sc = g1[c] * inv;
  zsc[c] = sc;
  zsc[128 + c] = bt1[c] - mu * sc;
}

__global__ __launch_bounds__(128) void k_out(const float* __restrict__ z1,
                                             const float* __restrict__ zsc,
                                             const float* __restrict__ W2,
                                             const float* __restrict__ b2,
                                             float* __restrict__ out) {
  __shared__ float zr[128];
  const int g = blockIdx.x;
  const int c = threadIdx.x;
  zr[c] = fmaxf(fmaf(z1[(size_t)g * 128 + c], zsc[c], zsc[128 + c]), 0.f);
  __syncthreads();
  if (c < OUTC) {
    float acc = b2[c];
    for (int k = 0; k < 128; ++k) acc = fmaf(zr[k], W2[k * OUTC + c], acc);
    out[(size_t)g * OUTC + c] = acc;
  }
}

// ---------- launch ----------

extern "C" void kernel_launch(void* const* d_in, const int* in_sizes, int n_in,
                              void* d_out, int out_size, void* d_ws, size_t ws_size,
                              hipStream_t stream) {
  const float* x      = (const float*)d_in[0];
  const int*   ei     = (const int*)d_in[1];
  const int*   batch  = (const int*)d_in[2];
  const float* Ws     = (const float*)d_in[3];
  const float* bs     = (const float*)d_in[4];
  const float* gammas = (const float*)d_in[5];
  const float* betas  = (const float*)d_in[6];
  const float* W1     = (const float*)d_in[7];
  const float* b1     = (const float*)d_in[8];
  const float* g1     = (const float*)d_in[9];
  const float* bt1    = (const float*)d_in[10];
  const float* W2     = (const float*)d_in[11];
  const float* b2     = (const float*)d_in[12];
  float* out = (float*)d_out;

  char* ws = (char*)d_ws;
  size_t off = 0;
  auto alloc = [&](size_t bytes) -> void* {
    void* p = ws + off;
    off = (off + bytes + 255) & ~(size_t)255;
    return p;
  };
  // zero-initialized region (single memset)
  int*   deg    = (int*)alloc((size_t)NN * 4);
  int*   cnt    = (int*)alloc((size_t)NN * 4);
  float* bnbuf  = (float*)alloc((size_t)LL * 256 * 4);
  float* pooled = (float*)alloc((size_t)GG * 512 * 4);
  size_t zero_bytes = off;
  // rest
  unsigned* Ar     = (unsigned*)alloc((size_t)NN * 64 * 4); // packed bf16 relu output
  unsigned* Ab     = (unsigned*)alloc((size_t)NN * 64 * 4); // packed bf16 GEMM input
  unsigned* Bb     = (unsigned*)alloc((size_t)NN * 64 * 4); // packed bf16 H@W (gather src)
  int2*     ecw    = (int2*)alloc((size_t)EE * 8);
  float*    dinv   = (float*)alloc((size_t)NN * 4);
  int*      rowptr = (int*)alloc((size_t)(NN + 1) * 4);
  int*      bsum   = (int*)alloc((size_t)NSCB * 4);
  int*      gstart = (int*)alloc((size_t)(GG + 1) * 4);
  uint4*    Wf     = (uint4*)alloc((size_t)LL * 4096 * 16); // MFMA W fragments (hi/lo)
  float*    z1     = (float*)alloc((size_t)GG * FF * 4);
  float*    bnsc   = (float*)alloc(256 * 4);
  float*    zsc    = (float*)alloc(256 * 4);
  (void)ws_size; (void)in_sizes; (void)n_in; (void)out_size;

  hipMemsetAsync(d_ws, 0, zero_bytes, stream);

  k_deg<<<(EE + 255) / 256, 256, 0, stream>>>(ei + EE, deg);
  k_dinv<<<(NN + 255) / 256, 256, 0, stream>>>(deg, dinv);
  k_bsum<<<NSCB, 256, 0, stream>>>(deg, bsum);
  k_rowptr<<<NSCB, 256, 0, stream>>>(deg, bsum, rowptr);
  k_fill<<<(EE + 255) / 256, 256, 0, stream>>>(ei, rowptr, cnt, dinv, ecw);
  k_bounds<<<(NN + 255) / 256, 256, 0, stream>>>(batch, gstart);
  k_cvt<<<(NN * 64 + 255) / 256, 256, 0, stream>>>(x, Ab);
  k_wcvt<<<64, 256, 0, stream>>>(Ws, Wf);

  for (int t = 0; t < LL; ++t) {
    k_mm<<<(NN + 63) / 64, 256, 0, stream>>>(Ab, Wf + (size_t)t * 4096, Bb);
    k_agg<<<2048, 256, 0, stream>>>(Bb, rowptr, ecw, bs + t * FF, Ar, bnbuf + t * 256);
    k_bnfin<<<1, 128, 0, stream>>>(bnbuf + t * 256, gammas + t * FF, betas + t * FF, bnsc);
    k_bnapply<<<GG * 8, 128, 0, stream>>>(Ar, bnsc, gstart, pooled + t * FF, Ab);
  }

  k_z1<<<GG, 128, 0, stream>>>(pooled, W1, b1, z1);
  k_zstat<<<1, 128, 0, stream>>>(z1, g1, bt1, zsc);
  k_out<<<GG, 128, 0, stream>>>(z1, zsc, W2, b2, out);
}